// Round 4
// baseline (440.732 us; speedup 1.0000x reference)
//
#include <hip/hip_runtime.h>
#include <hip/hip_bf16.h>

// Problem dims (fixed): T=1024 B=8 E=1024 H=16 hd=64 R=16, M=T*B=8192, F=3*E=3072
// Inputs f32 (runtime-detected; bf16 fallback). Intermediates bf16, fp32 accum.

typedef __attribute__((ext_vector_type(8))) __bf16 bf16x8;
typedef __attribute__((ext_vector_type(4))) float f32x4;

__device__ __forceinline__ float bf2f(unsigned short u) {
  union { unsigned int i; float f; } v; v.i = ((unsigned int)u) << 16; return v.f;
}
__device__ __forceinline__ unsigned short f2bf(float f) {
  union { float f; unsigned int i; } v; v.f = f;
  unsigned int x = v.i;
  unsigned int r = x + 0x7FFFu + ((x >> 16) & 1u);
  return (unsigned short)(r >> 16);
}
__device__ __forceinline__ unsigned int pack2(float a, float b) {
  return (unsigned int)f2bf(a) | ((unsigned int)f2bf(b) << 16);
}
__device__ __forceinline__ float ld_in(const void* p, long idx, int isf32) {
  if (isf32) return ((const float*)p)[idx];
  return bf2f(((const unsigned short*)p)[idx]);
}
// async global->LDS, 16 B per lane; LDS dst = wave-uniform base + lane*16
__device__ __forceinline__ void gl_lds16(const unsigned short* g, unsigned short* l) {
  __builtin_amdgcn_global_load_lds(
      (const __attribute__((address_space(1))) unsigned int*)g,
      (__attribute__((address_space(3))) unsigned int*)l, 16, 0, 0);
}

// ---------------------------------------------------------------------------
// Kernel 0: dtype detector (f32-stored vs bf16-packed).
__global__ void detect_kernel(const unsigned int* __restrict__ q, int* __restrict__ flag) {
  __shared__ int cnt;
  if (threadIdx.x == 0) cnt = 0;
  __syncthreads();
  unsigned int w = q[threadIdx.x];
  int c = 0;
  if (((w >> 7) & 0xFFu) >= 0xC0u) c++;
  if (((w >> 23) & 0xFFu) >= 0xC0u) c++;
  atomicAdd(&cnt, c);
  __syncthreads();
  if (threadIdx.x == 0) flag[0] = (cnt >= 2) ? 1 : 0;
}

// ---------------------------------------------------------------------------
// Kernel 0b: any f32 buffer -> bf16 (8 elems/thread). If !isf32, plain copy.
__global__ __launch_bounds__(256) void convert_bf16(
    const void* __restrict__ in, unsigned short* __restrict__ out,
    const int* __restrict__ flag) {
  long idx = ((long)blockIdx.x * 256 + threadIdx.x) * 8;
  if (flag[0]) {
    const float* p = (const float*)in + idx;
    float4 a = ((const float4*)p)[0], b = ((const float4*)p)[1];
    uint4 v;
    v.x = pack2(a.x, a.y); v.y = pack2(a.z, a.w);
    v.z = pack2(b.x, b.y); v.w = pack2(b.z, b.w);
    *(uint4*)(out + idx) = v;
  } else {
    *(uint4*)(out + idx) = *(const uint4*)((const unsigned short*)in + idx);
  }
}

// ---------------------------------------------------------------------------
// Kernel 1: W_eff = W + left @ right (rank-16), bf16 out.
__global__ __launch_bounds__(256) void eff_weights(
    const void* __restrict__ w, const void* __restrict__ left,
    const void* __restrict__ right, unsigned short* __restrict__ outw,
    const int* __restrict__ flag) {
  const int isf32 = flag[0];
  long idx = (long)blockIdx.x * 256 + threadIdx.x;
  long f = idx >> 10, e = idx & 1023;
  float acc = ld_in(w, idx, isf32);
#pragma unroll
  for (int r = 0; r < 16; ++r)
    acc += ld_in(left, (f << 4) + r, isf32) * ld_in(right, (r << 10) + e, isf32);
  outw[idx] = f2bf(acc);
}

// ---------------------------------------------------------------------------
// Kernel 2: in-proj GEMM, 128x128 tile, BK=32, global_load_lds staging into
// unpadded [128][32] LDS (64B row stride: b128 frag reads bank-uniform).
// v3: K-loop converted to T3 minimal 2-phase — As/Bs double-buffered, next
// K-step staged into buf^1 at TOP of iter, one __syncthreads per iter (its
// vmcnt(0) drain = RAW fence for buf^1; prev barrier = WAR fence). Was:
// stage->sync->compute->sync exposing full stage latency x32 iters
// (counters: MfmaUtil 17%, VALUBusy 12%, HBM 15% — latency-bound).
// Scatter epilogue to q (B,H,T,64)*0.125, k (B,H,T,64), v^T (B,H,64,T).
__global__ __launch_bounds__(256) void inproj_kernel(
    const unsigned short* __restrict__ qbf,    // (8192,1024) bf16
    const unsigned short* __restrict__ weff,   // (3072,1024) bf16
    const void* __restrict__ bias,             // (3072)
    unsigned short* __restrict__ qh, unsigned short* __restrict__ kh,
    unsigned short* __restrict__ vt, const int* __restrict__ flag) {
  __shared__ __align__(16) unsigned short As[2][128 * 32];
  __shared__ __align__(16) unsigned short Bs[2][128 * 32];
  const int isf32 = flag[0];
  const int tid = threadIdx.x;
  const int wave = tid >> 6, lane = tid & 63, quad = lane >> 4, lrow = lane & 15;
  const int wr0 = (wave >> 1) * 64, wc0 = (wave & 1) * 64;
  const int fbase = blockIdx.x * 128, mbase = blockIdx.y * 128;
  // staging: wave stages rows [32w,32w+16) and [32w+16,32w+32); lane covers
  // row 32w+16i+(lane>>2), cols (lane&3)*8..+8  (16B per lane, contiguous LDS)
  const int srow = lane >> 2, scol = (lane & 3) * 8;
  const unsigned short* ag  = qbf  + (long)(mbase + 32 * wave + srow) * 1024 + scol;
  const unsigned short* ag2 = ag + 16 * 1024;
  const unsigned short* bg  = weff + (long)(fbase + 32 * wave + srow) * 1024 + scol;
  const unsigned short* bg2 = bg + 16 * 1024;
  const int lof  = (32 * wave) * 32;
  const int lof2 = (32 * wave + 16) * 32;

  f32x4 acc[4][4] = {};
  // prologue: stage K-step 0 into buf 0; barrier drains vmcnt.
  gl_lds16(ag, &As[0][lof]);
  gl_lds16(ag2, &As[0][lof2]);
  gl_lds16(bg, &Bs[0][lof]);
  gl_lds16(bg2, &Bs[0][lof2]);
  __syncthreads();

  for (int it = 0; it < 32; ++it) {
    const int cur = it & 1;
    if (it < 31) {               // prefetch next K-step into buf^1
      const int kn = (it + 1) * 32;
      gl_lds16(ag + kn, &As[cur ^ 1][lof]);
      gl_lds16(ag2 + kn, &As[cur ^ 1][lof2]);
      gl_lds16(bg + kn, &Bs[cur ^ 1][lof]);
      gl_lds16(bg2 + kn, &Bs[cur ^ 1][lof2]);
    }
    bf16x8 af[4], bfv[4];
#pragma unroll
    for (int mi = 0; mi < 4; ++mi)
      af[mi] = *(const bf16x8*)&As[cur][(wr0 + mi * 16 + lrow) * 32 + quad * 8];
#pragma unroll
    for (int ni = 0; ni < 4; ++ni)
      bfv[ni] = *(const bf16x8*)&Bs[cur][(wc0 + ni * 16 + lrow) * 32 + quad * 8];
#pragma unroll
    for (int mi = 0; mi < 4; ++mi)
#pragma unroll
      for (int ni = 0; ni < 4; ++ni)
        acc[mi][ni] = __builtin_amdgcn_mfma_f32_16x16x32_bf16(af[mi], bfv[ni], acc[mi][ni], 0, 0, 0);
    __syncthreads();             // vmcnt(0): buf^1 staged; WAR fence for flip
  }
  const int which = fbase >> 10;               // 0=q 1=k 2=v (uniform per block)
  const int h = ((fbase + wc0) >> 6) & 15;     // wave's 64 cols = one head
#pragma unroll
  for (int ni = 0; ni < 4; ++ni) {
    const int d = ni * 16 + lrow;
    const float bv = ld_in(bias, fbase + wc0 + d, isf32);
#pragma unroll
    for (int mi = 0; mi < 4; ++mi)
#pragma unroll
      for (int r = 0; r < 4; ++r) {
        const int m = mbase + wr0 + mi * 16 + quad * 4 + r;
        const int t = m >> 3, b = m & 7;
        const float val = acc[mi][ni][r] + bv;
        if (which == 0)
          qh[((long)(b * 16 + h) * 1024 + t) * 64 + d] = f2bf(val * 0.125f);
        else if (which == 1)
          kh[((long)(b * 16 + h) * 1024 + t) * 64 + d] = f2bf(val);
        else
          vt[((long)(b * 16 + h) * 64 + d) * 1024 + t] = f2bf(val);
      }
  }
}

// ---------------------------------------------------------------------------
// Kernel 3: attention per (b,h, 64-row q-tile); s-tiles of 64.
// (unchanged from v2b — 2-phase K/V dbuf via global_load_lds, register bias
// prefetch, swizzled Ps; measured ~100 us inferred, no longer top-5.)
__global__ __launch_bounds__(256) void attn_kernel(
    const unsigned short* __restrict__ qh, const unsigned short* __restrict__ kh,
    const unsigned short* __restrict__ vt, const void* __restrict__ rpb,
    const unsigned short* __restrict__ pre,  // bf16 bias copy or nullptr
    unsigned short* __restrict__ ctx, const int* __restrict__ flag) {
  __shared__ __align__(16) unsigned short Ks[2][4096];  // [buf][kk*2048 + s*32 + d']
  __shared__ __align__(16) unsigned short Vs[2][4096];  // [buf][kk*2048 + d*32 + s']
  __shared__ __align__(16) unsigned short Ps[4][1024];  // [wave][swizzled row*64+col]
  const int isf32 = flag[0];
  const int tid = threadIdx.x;
  const int wave = tid >> 6, lane = tid & 63, quad = lane >> 4, lrow = lane & 15;
  const int b = blockIdx.y & 7, h = blockIdx.y >> 3, bh = b * 16 + h;
  const int t0 = blockIdx.x * 64;

  const unsigned short* qbase = qh + ((long)(bh * 1024) + t0 + wave * 16 + lrow) * 64;
  bf16x8 qf0 = *(const bf16x8*)(qbase + quad * 8);
  bf16x8 qf1 = *(const bf16x8*)(qbase + 32 + quad * 8);

  const unsigned short* kbase = kh + (long)bh * 65536;
  const unsigned short* vbase = vt + (long)bh * 65536;

  // bias element (r,n) at s-tile s0: bidx0 + r*1024 + s0 + n*16
  const long bidx0 = ((long)h * 1024 + t0 + wave * 16 + quad * 4) * 1024 + lrow;
  const unsigned short* bs16 = pre ? pre : (const unsigned short*)rpb;
  const bool bf32 = (isf32 && pre == nullptr);
  const float* bsf = (const float*)rpb;

  // staging: wave issues jobs j=2w,2w+1 for BOTH K and V.
  // j -> kk=j>>2 (32-col half), ii=j&3 (16-row chunk). K rows = s (stride 64),
  // V rows = d (stride 1024; cols t contiguous -> 16-segment coalesced).
  const int j0 = 2 * wave, j1 = j0 + 1;
  const int kk0 = j0 >> 2, ii0 = j0 & 3, kk1 = j1 >> 2, ii1 = j1 & 3;
  const int sr = lane >> 2, sc = (lane & 3) * 8;
  const unsigned short* kg0 = kbase + (long)(16 * ii0 + sr) * 64 + kk0 * 32 + sc;
  const unsigned short* kg1 = kbase + (long)(16 * ii1 + sr) * 64 + kk1 * 32 + sc;
  const unsigned short* vg0 = vbase + (long)(16 * ii0 + sr) * 1024 + kk0 * 32 + sc;
  const unsigned short* vg1 = vbase + (long)(16 * ii1 + sr) * 1024 + kk1 * 32 + sc;
  const int lo0 = kk0 * 2048 + ii0 * 512, lo1 = kk1 * 2048 + ii1 * 512;

  f32x4 oacc[4] = {};
  float rsum[4] = {0.f, 0.f, 0.f, 0.f};
  unsigned int bcur[4][4], bnxt[4][4];

  // prologue: stage tile 0 (K+V) and load bias(0); barrier drains vmcnt.
  gl_lds16(kg0, &Ks[0][lo0]);
  gl_lds16(kg1, &Ks[0][lo1]);
  gl_lds16(vg0, &Vs[0][lo0]);
  gl_lds16(vg1, &Vs[0][lo1]);
  if (bf32) {
#pragma unroll
    for (int r = 0; r < 4; ++r)
#pragma unroll
      for (int n = 0; n < 4; ++n)
        bcur[r][n] = __float_as_uint(bsf[bidx0 + r * 1024 + n * 16]);
  } else {
#pragma unroll
    for (int r = 0; r < 4; ++r)
#pragma unroll
      for (int n = 0; n < 4; ++n)
        bcur[r][n] = (unsigned int)bs16[bidx0 + r * 1024 + n * 16];
  }
  __syncthreads();

  for (int t = 0; t < 16; ++t) {
    const int cur = t & 1;
    const int s0 = t << 6;
    if (t < 15) {            // prefetch next tile: K,V -> LDS buf^1, bias -> regs
      const int sn = s0 + 64;
      gl_lds16(kg0 + (long)sn * 64, &Ks[cur ^ 1][lo0]);
      gl_lds16(kg1 + (long)sn * 64, &Ks[cur ^ 1][lo1]);
      gl_lds16(vg0 + sn, &Vs[cur ^ 1][lo0]);
      gl_lds16(vg1 + sn, &Vs[cur ^ 1][lo1]);
      if (bf32) {
#pragma unroll
        for (int r = 0; r < 4; ++r)
#pragma unroll
          for (int n = 0; n < 4; ++n)
            bnxt[r][n] = __float_as_uint(bsf[bidx0 + r * 1024 + sn + n * 16]);
      } else {
#pragma unroll
        for (int r = 0; r < 4; ++r)
#pragma unroll
          for (int n = 0; n < 4; ++n)
            bnxt[r][n] = (unsigned int)bs16[bidx0 + r * 1024 + sn + n * 16];
      }
    }

    f32x4 sacc[4] = {};
#pragma unroll
    for (int n = 0; n < 4; ++n) {
      bf16x8 kf0 = *(const bf16x8*)&Ks[cur][(n * 16 + lrow) * 32 + quad * 8];
      bf16x8 kf1 = *(const bf16x8*)&Ks[cur][2048 + (n * 16 + lrow) * 32 + quad * 8];
      sacc[n] = __builtin_amdgcn_mfma_f32_16x16x32_bf16(qf0, kf0, sacc[n], 0, 0, 0);
      sacc[n] = __builtin_amdgcn_mfma_f32_16x16x32_bf16(qf1, kf1, sacc[n], 0, 0, 0);
    }

#pragma unroll
    for (int n = 0; n < 4; ++n)
#pragma unroll
      for (int r = 0; r < 4; ++r) {
        const int row = quad * 4 + r;
        const float bv = bf32 ? __uint_as_float(bcur[r][n])
                              : bf2f((unsigned short)bcur[r][n]);
        const float p = __expf(sacc[n][r] + bv);
        rsum[r] += p;
        Ps[wave][(row * 64 + n * 16 + lrow) ^ ((row & 7) << 3)] = f2bf(p);
      }

    asm volatile("s_waitcnt lgkmcnt(0)" ::: "memory");  // Ps writes visible (same wave)

#pragma unroll
    for (int kk = 0; kk < 2; ++kk) {
      bf16x8 pf = *(const bf16x8*)&Ps[wave][(lrow * 64 + kk * 32 + quad * 8) ^ ((lrow & 7) << 3)];
#pragma unroll
      for (int n = 0; n < 4; ++n) {
        bf16x8 vf = *(const bf16x8*)&Vs[cur][kk * 2048 + (n * 16 + lrow) * 32 + quad * 8];
        oacc[n] = __builtin_amdgcn_mfma_f32_16x16x32_bf16(pf, vf, oacc[n], 0, 0, 0);
      }
    }
    __syncthreads();   // vmcnt(0): next-tile stage landed; WAR fence for buf flip
    if (t < 15) {
#pragma unroll
      for (int r = 0; r < 4; ++r)
#pragma unroll
        for (int n = 0; n < 4; ++n) bcur[r][n] = bnxt[r][n];
    }
  }

  // single deferred reduction: sum over the 16 lanes (lrow) sharing this quad
#pragma unroll
  for (int msk = 1; msk <= 8; msk <<= 1)
#pragma unroll
    for (int r = 0; r < 4; ++r)
      rsum[r] += __shfl_xor(rsum[r], msk, 64);

  float linv[4];
#pragma unroll
  for (int r = 0; r < 4; ++r) linv[r] = 1.0f / rsum[r];
#pragma unroll
  for (int n = 0; n < 4; ++n)
#pragma unroll
    for (int r = 0; r < 4; ++r) {
      const int t = t0 + wave * 16 + quad * 4 + r;
      ctx[((long)t * 8 + b) * 1024 + h * 64 + n * 16 + lrow] = f2bf(oacc[n][r] * linv[r]);
    }
}

// ---------------------------------------------------------------------------
// Kernel 4: out-proj GEMM, 128x128 tile, BK=32; v3: same T3 2-phase dbuf
// as inproj (was 1-phase, same latency exposure).
__global__ __launch_bounds__(256) void outproj_kernel(
    const unsigned short* __restrict__ ctx, const unsigned short* __restrict__ weff,
    const void* __restrict__ bias, void* __restrict__ out,
    const int* __restrict__ flag) {
  __shared__ __align__(16) unsigned short As[2][128 * 32];
  __shared__ __align__(16) unsigned short Bs[2][128 * 32];
  const int isf32 = flag[0];
  const int tid = threadIdx.x;
  const int wave = tid >> 6, lane = tid & 63, quad = lane >> 4, lrow = lane & 15;
  const int wr0 = (wave >> 1) * 64, wc0 = (wave & 1) * 64;
  const int fbase = blockIdx.x * 128, mbase = blockIdx.y * 128;
  const int srow = lane >> 2, scol = (lane & 3) * 8;
  const unsigned short* ag  = ctx  + (long)(mbase + 32 * wave + srow) * 1024 + scol;
  const unsigned short* ag2 = ag + 16 * 1024;
  const unsigned short* bg  = weff + (long)(fbase + 32 * wave + srow) * 1024 + scol;
  const unsigned short* bg2 = bg + 16 * 1024;
  const int lof  = (32 * wave) * 32;
  const int lof2 = (32 * wave + 16) * 32;

  f32x4 acc[4][4] = {};
  gl_lds16(ag, &As[0][lof]);
  gl_lds16(ag2, &As[0][lof2]);
  gl_lds16(bg, &Bs[0][lof]);
  gl_lds16(bg2, &Bs[0][lof2]);
  __syncthreads();

  for (int it = 0; it < 32; ++it) {
    const int cur = it & 1;
    if (it < 31) {
      const int kn = (it + 1) * 32;
      gl_lds16(ag + kn, &As[cur ^ 1][lof]);
      gl_lds16(ag2 + kn, &As[cur ^ 1][lof2]);
      gl_lds16(bg + kn, &Bs[cur ^ 1][lof]);
      gl_lds16(bg2 + kn, &Bs[cur ^ 1][lof2]);
    }
    bf16x8 af[4], bfv[4];
#pragma unroll
    for (int mi = 0; mi < 4; ++mi)
      af[mi] = *(const bf16x8*)&As[cur][(wr0 + mi * 16 + lrow) * 32 + quad * 8];
#pragma unroll
    for (int ni = 0; ni < 4; ++ni)
      bfv[ni] = *(const bf16x8*)&Bs[cur][(wc0 + ni * 16 + lrow) * 32 + quad * 8];
#pragma unroll
    for (int mi = 0; mi < 4; ++mi)
#pragma unroll
      for (int ni = 0; ni < 4; ++ni)
        acc[mi][ni] = __builtin_amdgcn_mfma_f32_16x16x32_bf16(af[mi], bfv[ni], acc[mi][ni], 0, 0, 0);
    __syncthreads();
  }
#pragma unroll
  for (int ni = 0; ni < 4; ++ni) {
    const int f = fbase + wc0 + ni * 16 + lrow;
    const float bv = ld_in(bias, f, isf32);
#pragma unroll
    for (int mi = 0; mi < 4; ++mi)
#pragma unroll
      for (int r = 0; r < 4; ++r) {
        const int m = mbase + wr0 + mi * 16 + quad * 4 + r;
        const float val = acc[mi][ni][r] + bv;
        if (isf32) ((float*)out)[(long)m * 1024 + f] = val;
        else       ((unsigned short*)out)[(long)m * 1024 + f] = f2bf(val);
      }
  }
}

// ---------------------------------------------------------------------------
extern "C" void kernel_launch(void* const* d_in, const int* in_sizes, int n_in,
                              void* d_out, int out_size, void* d_ws, size_t ws_size,
                              hipStream_t stream) {
  (void)out_size;
  static const int EXP[10] = {8388608, 3145728, 3072, 49152, 16384,
                              1048576, 1024, 16384, 16384, 16777216};
  if (n_in != 10) return;
  for (int i = 0; i < 10; ++i) if (in_sizes[i] != EXP[i]) return;

  const void* query = d_in[0];
  const void* ipw = d_in[1];  const void* ipb = d_in[2];
  const void* il  = d_in[3];  const void* ir  = d_in[4];
  const void* opw = d_in[5];  const void* opb = d_in[6];
  const void* ol  = d_in[7];  const void* orr = d_in[8];
  const void* rpb = d_in[9];

  // ws: flag | W_in_eff 3072x1024 | W_out_eff 1024x1024 | q | k | vT | ctx
  //     (each 8192x1024) | rpb_bf16 16M.  qbf aliases ctx (dead until attn).
  int* flag = (int*)d_ws;
  unsigned short* base = (unsigned short*)d_ws + 16;
  unsigned short* w_in_eff  = base;
  unsigned short* w_out_eff = w_in_eff + (long)3072 * 1024;
  unsigned short* qh  = w_out_eff + (long)1024 * 1024;
  unsigned short* kh  = qh + 8388608L;
  unsigned short* vt  = kh + 8388608L;
  unsigned short* ctx = vt + 8388608L;
  unsigned short* rpbbf = ctx + 8388608L;
  unsigned short* qbf = ctx;  // alias: qbf consumed by inproj before attn writes ctx
  const size_t NEED_FULL = 32 + (3145728L + 1048576L + 4L * 8388608L + 16777216L) * 2;
  const bool big = ws_size >= NEED_FULL;

  detect_kernel<<<dim3(1), dim3(64), 0, stream>>>((const unsigned int*)query, flag);
  if (big)
    convert_bf16<<<dim3(8192), dim3(256), 0, stream>>>(rpb, rpbbf, flag);
  convert_bf16<<<dim3(4096), dim3(256), 0, stream>>>(query, qbf, flag);
  eff_weights<<<dim3(12288), dim3(256), 0, stream>>>(ipw, il, ir, w_in_eff, flag);
  eff_weights<<<dim3(4096), dim3(256), 0, stream>>>(opw, ol, orr, w_out_eff, flag);
  inproj_kernel<<<dim3(24, 64), dim3(256), 0, stream>>>(qbf, w_in_eff, ipb, qh, kh, vt, flag);
  attn_kernel<<<dim3(16, 128), dim3(256), 0, stream>>>(qh, kh, vt, rpb,
                                                       big ? rpbbf : nullptr, ctx, flag);
  outproj_kernel<<<dim3(8, 64), dim3(256), 0, stream>>>(ctx, w_out_eff, opb, d_out, flag);
}

// Round 5
// 417.638 us; speedup vs baseline: 1.0553x; 1.0553x over previous
//
#include <hip/hip_runtime.h>
#include <hip/hip_bf16.h>

// Problem dims (fixed): T=1024 B=8 E=1024 H=16 hd=64 R=16, M=T*B=8192, F=3*E=3072
// Inputs f32 (runtime-detected; bf16 fallback). Intermediates bf16, fp32 accum.

typedef __attribute__((ext_vector_type(8))) __bf16 bf16x8;
typedef __attribute__((ext_vector_type(4))) float f32x4;

__device__ __forceinline__ float bf2f(unsigned short u) {
  union { unsigned int i; float f; } v; v.i = ((unsigned int)u) << 16; return v.f;
}
__device__ __forceinline__ unsigned short f2bf(float f) {
  union { float f; unsigned int i; } v; v.f = f;
  unsigned int x = v.i;
  unsigned int r = x + 0x7FFFu + ((x >> 16) & 1u);
  return (unsigned short)(r >> 16);
}
__device__ __forceinline__ unsigned int pack2(float a, float b) {
  return (unsigned int)f2bf(a) | ((unsigned int)f2bf(b) << 16);
}
__device__ __forceinline__ float ld_in(const void* p, long idx, int isf32) {
  if (isf32) return ((const float*)p)[idx];
  return bf2f(((const unsigned short*)p)[idx]);
}
// async global->LDS, 16 B per lane; LDS dst = wave-uniform base + lane*16
__device__ __forceinline__ void gl_lds16(const unsigned short* g, unsigned short* l) {
  __builtin_amdgcn_global_load_lds(
      (const __attribute__((address_space(1))) unsigned int*)g,
      (__attribute__((address_space(3))) unsigned int*)l, 16, 0, 0);
}

// ---------------------------------------------------------------------------
// Kernel 0: dtype detector (f32-stored vs bf16-packed).
__global__ void detect_kernel(const unsigned int* __restrict__ q, int* __restrict__ flag) {
  __shared__ int cnt;
  if (threadIdx.x == 0) cnt = 0;
  __syncthreads();
  unsigned int w = q[threadIdx.x];
  int c = 0;
  if (((w >> 7) & 0xFFu) >= 0xC0u) c++;
  if (((w >> 23) & 0xFFu) >= 0xC0u) c++;
  atomicAdd(&cnt, c);
  __syncthreads();
  if (threadIdx.x == 0) flag[0] = (cnt >= 2) ? 1 : 0;
}

// ---------------------------------------------------------------------------
// Kernel 0b: any f32 buffer -> bf16 (8 elems/thread). If !isf32, plain copy.
__global__ __launch_bounds__(256) void convert_bf16(
    const void* __restrict__ in, unsigned short* __restrict__ out,
    const int* __restrict__ flag) {
  long idx = ((long)blockIdx.x * 256 + threadIdx.x) * 8;
  if (flag[0]) {
    const float* p = (const float*)in + idx;
    float4 a = ((const float4*)p)[0], b = ((const float4*)p)[1];
    uint4 v;
    v.x = pack2(a.x, a.y); v.y = pack2(a.z, a.w);
    v.z = pack2(b.x, b.y); v.w = pack2(b.z, b.w);
    *(uint4*)(out + idx) = v;
  } else {
    *(uint4*)(out + idx) = *(const uint4*)((const unsigned short*)in + idx);
  }
}

// ---------------------------------------------------------------------------
// Kernel 0c: query convert with row permutation (T,B,E) -> (B,T,E).
// Row in = t*8+b (2KB contiguous), row out = b*1024+t. Pure row permute:
// both sides stay 16B-chunk contiguous within a row. Makes b uniform per
// 128-row inproj tile and t contiguous -> vectorizable v^T epilogue stores.
__global__ __launch_bounds__(256) void convert_q(
    const void* __restrict__ in, unsigned short* __restrict__ out,
    const int* __restrict__ flag) {
  long idx = ((long)blockIdx.x * 256 + threadIdx.x) * 8;
  const int inrow = (int)(idx >> 10);
  const int e = (int)(idx & 1023);
  const long oidx = ((long)((inrow & 7) << 10 | (inrow >> 3))) * 1024 + e;
  if (flag[0]) {
    const float* p = (const float*)in + idx;
    float4 a = ((const float4*)p)[0], b = ((const float4*)p)[1];
    uint4 v;
    v.x = pack2(a.x, a.y); v.y = pack2(a.z, a.w);
    v.z = pack2(b.x, b.y); v.w = pack2(b.z, b.w);
    *(uint4*)(out + oidx) = v;
  } else {
    *(uint4*)(out + oidx) = *(const uint4*)((const unsigned short*)in + idx);
  }
}

// ---------------------------------------------------------------------------
// Kernel 1: W_eff = W + left @ right (rank-16), bf16 out.
__global__ __launch_bounds__(256) void eff_weights(
    const void* __restrict__ w, const void* __restrict__ left,
    const void* __restrict__ right, unsigned short* __restrict__ outw,
    const int* __restrict__ flag) {
  const int isf32 = flag[0];
  long idx = (long)blockIdx.x * 256 + threadIdx.x;
  long f = idx >> 10, e = idx & 1023;
  float acc = ld_in(w, idx, isf32);
#pragma unroll
  for (int r = 0; r < 16; ++r)
    acc += ld_in(left, (f << 4) + r, isf32) * ld_in(right, (r << 10) + e, isf32);
  outw[idx] = f2bf(acc);
}

// ---------------------------------------------------------------------------
// Kernel 2: in-proj GEMM, 128x128 tile, BK=32, 1-phase global_load_lds
// staging (v2 structure restored: explicit 2-phase dbuf REGRESSED 124->155us
// in R4 — per m99/m100, implicit wave-level overlap already fills the drain;
// dbuf added per-iter address VALU + same vmcnt(0) exposure).
// A rows are (b,t) layout: m = b*1024+t (b uniform per tile, t contiguous).
// Epilogue: q (B,H,T,64)*0.125, k (B,H,T,64) as 32B-segment scalar stores;
// v^T (B,H,64,T) as ushort4 stores (r -> 4 consecutive t), 16x32B segments
// per instruction (was 64x2B scatter).
__global__ __launch_bounds__(256) void inproj_kernel(
    const unsigned short* __restrict__ qbf,    // (8,1024,1024) bf16, row=b*1024+t
    const unsigned short* __restrict__ weff,   // (3072,1024) bf16
    const void* __restrict__ bias,             // (3072)
    unsigned short* __restrict__ qh, unsigned short* __restrict__ kh,
    unsigned short* __restrict__ vt, const int* __restrict__ flag) {
  __shared__ __align__(16) unsigned short As[128 * 32];
  __shared__ __align__(16) unsigned short Bs[128 * 32];
  const int isf32 = flag[0];
  const int tid = threadIdx.x;
  const int wave = tid >> 6, lane = tid & 63, quad = lane >> 4, lrow = lane & 15;
  const int wr0 = (wave >> 1) * 64, wc0 = (wave & 1) * 64;
  const int fbase = blockIdx.x * 128, mbase = blockIdx.y * 128;
  // staging: wave stages rows [32w,32w+16) and [32w+16,32w+32); lane covers
  // row 32w+16i+(lane>>2), cols (lane&3)*8..+8  (16B per lane, contiguous LDS)
  const int srow = lane >> 2, scol = (lane & 3) * 8;
  const unsigned short* ag  = qbf  + (long)(mbase + 32 * wave + srow) * 1024 + scol;
  const unsigned short* ag2 = ag + 16 * 1024;
  const unsigned short* bg  = weff + (long)(fbase + 32 * wave + srow) * 1024 + scol;
  const unsigned short* bg2 = bg + 16 * 1024;
  unsigned short* la  = &As[(32 * wave) * 32];
  unsigned short* la2 = &As[(32 * wave + 16) * 32];
  unsigned short* lb  = &Bs[(32 * wave) * 32];
  unsigned short* lb2 = &Bs[(32 * wave + 16) * 32];

  f32x4 acc[4][4] = {};
  for (int k0 = 0; k0 < 1024; k0 += 32) {
    gl_lds16(ag + k0, la);
    gl_lds16(ag2 + k0, la2);
    gl_lds16(bg + k0, lb);
    gl_lds16(bg2 + k0, lb2);
    __syncthreads();             // drains vmcnt: staged data visible
    bf16x8 af[4], bfv[4];
#pragma unroll
    for (int mi = 0; mi < 4; ++mi)
      af[mi] = *(const bf16x8*)&As[(wr0 + mi * 16 + lrow) * 32 + quad * 8];
#pragma unroll
    for (int ni = 0; ni < 4; ++ni)
      bfv[ni] = *(const bf16x8*)&Bs[(wc0 + ni * 16 + lrow) * 32 + quad * 8];
#pragma unroll
    for (int mi = 0; mi < 4; ++mi)
#pragma unroll
      for (int ni = 0; ni < 4; ++ni)
        acc[mi][ni] = __builtin_amdgcn_mfma_f32_16x16x32_bf16(af[mi], bfv[ni], acc[mi][ni], 0, 0, 0);
    __syncthreads();             // protect LDS before next stage
  }
  const int which = fbase >> 10;               // 0=q 1=k 2=v (uniform per block)
  const int h = ((fbase + wc0) >> 6) & 15;     // wave's 64 cols = one head
  const int bq = mbase >> 10;                  // uniform batch index per block
  const int tbase = (mbase & 1023) + wr0;
#pragma unroll
  for (int ni = 0; ni < 4; ++ni) {
    const int d = ni * 16 + lrow;
    const float bv = ld_in(bias, fbase + wc0 + d, isf32);
    if (which == 2) {
      unsigned short* vrow = vt + ((long)(bq * 16 + h) * 64 + d) * 1024;
#pragma unroll
      for (int mi = 0; mi < 4; ++mi) {
        const int t = tbase + mi * 16 + quad * 4;
        ushort4 v;
        v.x = f2bf(acc[mi][ni][0] + bv);
        v.y = f2bf(acc[mi][ni][1] + bv);
        v.z = f2bf(acc[mi][ni][2] + bv);
        v.w = f2bf(acc[mi][ni][3] + bv);
        *(ushort4*)(vrow + t) = v;
      }
    } else {
      unsigned short* qk = (which == 0) ? qh : kh;
      const float sc = (which == 0) ? 0.125f : 1.0f;
      unsigned short* row0 = qk + (long)(bq * 16 + h) * 65536;
#pragma unroll
      for (int mi = 0; mi < 4; ++mi)
#pragma unroll
        for (int r = 0; r < 4; ++r) {
          const int t = tbase + mi * 16 + quad * 4 + r;
          row0[(long)t * 64 + d] = f2bf((acc[mi][ni][r] + bv) * sc);
        }
    }
  }
}

// ---------------------------------------------------------------------------
// Kernel 3: attention per (b,h, 64-row q-tile); s-tiles of 64.
// (unchanged: 2-phase K/V dbuf via global_load_lds, register bias prefetch,
// swizzled Ps — R3-verified, no longer top-5.)
__global__ __launch_bounds__(256) void attn_kernel(
    const unsigned short* __restrict__ qh, const unsigned short* __restrict__ kh,
    const unsigned short* __restrict__ vt, const void* __restrict__ rpb,
    const unsigned short* __restrict__ pre,  // bf16 bias copy or nullptr
    unsigned short* __restrict__ ctx, const int* __restrict__ flag) {
  __shared__ __align__(16) unsigned short Ks[2][4096];  // [buf][kk*2048 + s*32 + d']
  __shared__ __align__(16) unsigned short Vs[2][4096];  // [buf][kk*2048 + d*32 + s']
  __shared__ __align__(16) unsigned short Ps[4][1024];  // [wave][swizzled row*64+col]
  const int isf32 = flag[0];
  const int tid = threadIdx.x;
  const int wave = tid >> 6, lane = tid & 63, quad = lane >> 4, lrow = lane & 15;
  const int b = blockIdx.y & 7, h = blockIdx.y >> 3, bh = b * 16 + h;
  const int t0 = blockIdx.x * 64;

  const unsigned short* qbase = qh + ((long)(bh * 1024) + t0 + wave * 16 + lrow) * 64;
  bf16x8 qf0 = *(const bf16x8*)(qbase + quad * 8);
  bf16x8 qf1 = *(const bf16x8*)(qbase + 32 + quad * 8);

  const unsigned short* kbase = kh + (long)bh * 65536;
  const unsigned short* vbase = vt + (long)bh * 65536;

  // bias element (r,n) at s-tile s0: bidx0 + r*1024 + s0 + n*16
  const long bidx0 = ((long)h * 1024 + t0 + wave * 16 + quad * 4) * 1024 + lrow;
  const unsigned short* bs16 = pre ? pre : (const unsigned short*)rpb;
  const bool bf32 = (isf32 && pre == nullptr);
  const float* bsf = (const float*)rpb;

  // staging: wave issues jobs j=2w,2w+1 for BOTH K and V.
  // j -> kk=j>>2 (32-col half), ii=j&3 (16-row chunk). K rows = s (stride 64),
  // V rows = d (stride 1024; cols t contiguous -> 16-segment coalesced).
  const int j0 = 2 * wave, j1 = j0 + 1;
  const int kk0 = j0 >> 2, ii0 = j0 & 3, kk1 = j1 >> 2, ii1 = j1 & 3;
  const int sr = lane >> 2, sc = (lane & 3) * 8;
  const unsigned short* kg0 = kbase + (long)(16 * ii0 + sr) * 64 + kk0 * 32 + sc;
  const unsigned short* kg1 = kbase + (long)(16 * ii1 + sr) * 64 + kk1 * 32 + sc;
  const unsigned short* vg0 = vbase + (long)(16 * ii0 + sr) * 1024 + kk0 * 32 + sc;
  const unsigned short* vg1 = vbase + (long)(16 * ii1 + sr) * 1024 + kk1 * 32 + sc;
  const int lo0 = kk0 * 2048 + ii0 * 512, lo1 = kk1 * 2048 + ii1 * 512;

  f32x4 oacc[4] = {};
  float rsum[4] = {0.f, 0.f, 0.f, 0.f};
  unsigned int bcur[4][4], bnxt[4][4];

  // prologue: stage tile 0 (K+V) and load bias(0); barrier drains vmcnt.
  gl_lds16(kg0, &Ks[0][lo0]);
  gl_lds16(kg1, &Ks[0][lo1]);
  gl_lds16(vg0, &Vs[0][lo0]);
  gl_lds16(vg1, &Vs[0][lo1]);
  if (bf32) {
#pragma unroll
    for (int r = 0; r < 4; ++r)
#pragma unroll
      for (int n = 0; n < 4; ++n)
        bcur[r][n] = __float_as_uint(bsf[bidx0 + r * 1024 + n * 16]);
  } else {
#pragma unroll
    for (int r = 0; r < 4; ++r)
#pragma unroll
      for (int n = 0; n < 4; ++n)
        bcur[r][n] = (unsigned int)bs16[bidx0 + r * 1024 + n * 16];
  }
  __syncthreads();

  for (int t = 0; t < 16; ++t) {
    const int cur = t & 1;
    const int s0 = t << 6;
    if (t < 15) {            // prefetch next tile: K,V -> LDS buf^1, bias -> regs
      const int sn = s0 + 64;
      gl_lds16(kg0 + (long)sn * 64, &Ks[cur ^ 1][lo0]);
      gl_lds16(kg1 + (long)sn * 64, &Ks[cur ^ 1][lo1]);
      gl_lds16(vg0 + sn, &Vs[cur ^ 1][lo0]);
      gl_lds16(vg1 + sn, &Vs[cur ^ 1][lo1]);
      if (bf32) {
#pragma unroll
        for (int r = 0; r < 4; ++r)
#pragma unroll
          for (int n = 0; n < 4; ++n)
            bnxt[r][n] = __float_as_uint(bsf[bidx0 + r * 1024 + sn + n * 16]);
      } else {
#pragma unroll
        for (int r = 0; r < 4; ++r)
#pragma unroll
          for (int n = 0; n < 4; ++n)
            bnxt[r][n] = (unsigned int)bs16[bidx0 + r * 1024 + sn + n * 16];
      }
    }

    f32x4 sacc[4] = {};
#pragma unroll
    for (int n = 0; n < 4; ++n) {
      bf16x8 kf0 = *(const bf16x8*)&Ks[cur][(n * 16 + lrow) * 32 + quad * 8];
      bf16x8 kf1 = *(const bf16x8*)&Ks[cur][2048 + (n * 16 + lrow) * 32 + quad * 8];
      sacc[n] = __builtin_amdgcn_mfma_f32_16x16x32_bf16(qf0, kf0, sacc[n], 0, 0, 0);
      sacc[n] = __builtin_amdgcn_mfma_f32_16x16x32_bf16(qf1, kf1, sacc[n], 0, 0, 0);
    }

#pragma unroll
    for (int n = 0; n < 4; ++n)
#pragma unroll
      for (int r = 0; r < 4; ++r) {
        const int row = quad * 4 + r;
        const float bv = bf32 ? __uint_as_float(bcur[r][n])
                              : bf2f((unsigned short)bcur[r][n]);
        const float p = __expf(sacc[n][r] + bv);
        rsum[r] += p;
        Ps[wave][(row * 64 + n * 16 + lrow) ^ ((row & 7) << 3)] = f2bf(p);
      }

    asm volatile("s_waitcnt lgkmcnt(0)" ::: "memory");  // Ps writes visible (same wave)

#pragma unroll
    for (int kk = 0; kk < 2; ++kk) {
      bf16x8 pf = *(const bf16x8*)&Ps[wave][(lrow * 64 + kk * 32 + quad * 8) ^ ((lrow & 7) << 3)];
#pragma unroll
      for (int n = 0; n < 4; ++n) {
        bf16x8 vf = *(const bf16x8*)&Vs[cur][kk * 2048 + (n * 16 + lrow) * 32 + quad * 8];
        oacc[n] = __builtin_amdgcn_mfma_f32_16x16x32_bf16(pf, vf, oacc[n], 0, 0, 0);
      }
    }
    __syncthreads();   // vmcnt(0): next-tile stage landed; WAR fence for buf flip
    if (t < 15) {
#pragma unroll
      for (int r = 0; r < 4; ++r)
#pragma unroll
        for (int n = 0; n < 4; ++n) bcur[r][n] = bnxt[r][n];
    }
  }

  // single deferred reduction: sum over the 16 lanes (lrow) sharing this quad
#pragma unroll
  for (int msk = 1; msk <= 8; msk <<= 1)
#pragma unroll
    for (int r = 0; r < 4; ++r)
      rsum[r] += __shfl_xor(rsum[r], msk, 64);

  float linv[4];
#pragma unroll
  for (int r = 0; r < 4; ++r) linv[r] = 1.0f / rsum[r];
#pragma unroll
  for (int n = 0; n < 4; ++n)
#pragma unroll
    for (int r = 0; r < 4; ++r) {
      const int t = t0 + wave * 16 + quad * 4 + r;
      ctx[((long)t * 8 + b) * 1024 + h * 64 + n * 16 + lrow] = f2bf(oacc[n][r] * linv[r]);
    }
}

// ---------------------------------------------------------------------------
// Kernel 4: out-proj GEMM, 128x128 tile, BK=32, 1-phase global_load_lds
// staging (v2 structure restored — see inproj comment).
__global__ __launch_bounds__(256) void outproj_kernel(
    const unsigned short* __restrict__ ctx, const unsigned short* __restrict__ weff,
    const void* __restrict__ bias, void* __restrict__ out,
    const int* __restrict__ flag) {
  __shared__ __align__(16) unsigned short As[128 * 32];
  __shared__ __align__(16) unsigned short Bs[128 * 32];
  const int isf32 = flag[0];
  const int tid = threadIdx.x;
  const int wave = tid >> 6, lane = tid & 63, quad = lane >> 4, lrow = lane & 15;
  const int wr0 = (wave >> 1) * 64, wc0 = (wave & 1) * 64;
  const int fbase = blockIdx.x * 128, mbase = blockIdx.y * 128;
  const int srow = lane >> 2, scol = (lane & 3) * 8;
  const unsigned short* ag  = ctx  + (long)(mbase + 32 * wave + srow) * 1024 + scol;
  const unsigned short* ag2 = ag + 16 * 1024;
  const unsigned short* bg  = weff + (long)(fbase + 32 * wave + srow) * 1024 + scol;
  const unsigned short* bg2 = bg + 16 * 1024;
  unsigned short* la  = &As[(32 * wave) * 32];
  unsigned short* la2 = &As[(32 * wave + 16) * 32];
  unsigned short* lb  = &Bs[(32 * wave) * 32];
  unsigned short* lb2 = &Bs[(32 * wave + 16) * 32];

  f32x4 acc[4][4] = {};
  for (int k0 = 0; k0 < 1024; k0 += 32) {
    gl_lds16(ag + k0, la);
    gl_lds16(ag2 + k0, la2);
    gl_lds16(bg + k0, lb);
    gl_lds16(bg2 + k0, lb2);
    __syncthreads();
    bf16x8 af[4], bfv[4];
#pragma unroll
    for (int mi = 0; mi < 4; ++mi)
      af[mi] = *(const bf16x8*)&As[(wr0 + mi * 16 + lrow) * 32 + quad * 8];
#pragma unroll
    for (int ni = 0; ni < 4; ++ni)
      bfv[ni] = *(const bf16x8*)&Bs[(wc0 + ni * 16 + lrow) * 32 + quad * 8];
#pragma unroll
    for (int mi = 0; mi < 4; ++mi)
#pragma unroll
      for (int ni = 0; ni < 4; ++ni)
        acc[mi][ni] = __builtin_amdgcn_mfma_f32_16x16x32_bf16(af[mi], bfv[ni], acc[mi][ni], 0, 0, 0);
    __syncthreads();
  }
#pragma unroll
  for (int ni = 0; ni < 4; ++ni) {
    const int f = fbase + wc0 + ni * 16 + lrow;
    const float bv = ld_in(bias, f, isf32);
#pragma unroll
    for (int mi = 0; mi < 4; ++mi)
#pragma unroll
      for (int r = 0; r < 4; ++r) {
        const int m = mbase + wr0 + mi * 16 + quad * 4 + r;
        const float val = acc[mi][ni][r] + bv;
        if (isf32) ((float*)out)[(long)m * 1024 + f] = val;
        else       ((unsigned short*)out)[(long)m * 1024 + f] = f2bf(val);
      }
  }
}

// ---------------------------------------------------------------------------
extern "C" void kernel_launch(void* const* d_in, const int* in_sizes, int n_in,
                              void* d_out, int out_size, void* d_ws, size_t ws_size,
                              hipStream_t stream) {
  (void)out_size;
  static const int EXP[10] = {8388608, 3145728, 3072, 49152, 16384,
                              1048576, 1024, 16384, 16384, 16777216};
  if (n_in != 10) return;
  for (int i = 0; i < 10; ++i) if (in_sizes[i] != EXP[i]) return;

  const void* query = d_in[0];
  const void* ipw = d_in[1];  const void* ipb = d_in[2];
  const void* il  = d_in[3];  const void* ir  = d_in[4];
  const void* opw = d_in[5];  const void* opb = d_in[6];
  const void* ol  = d_in[7];  const void* orr = d_in[8];
  const void* rpb = d_in[9];

  // ws: flag | W_in_eff 3072x1024 | W_out_eff 1024x1024 | q | k | vT | ctx
  //     (each 8192x1024) | rpb_bf16 16M.  qbf aliases ctx (dead until attn).
  int* flag = (int*)d_ws;
  unsigned short* base = (unsigned short*)d_ws + 16;
  unsigned short* w_in_eff  = base;
  unsigned short* w_out_eff = w_in_eff + (long)3072 * 1024;
  unsigned short* qh  = w_out_eff + (long)1024 * 1024;
  unsigned short* kh  = qh + 8388608L;
  unsigned short* vt  = kh + 8388608L;
  unsigned short* ctx = vt + 8388608L;
  unsigned short* rpbbf = ctx + 8388608L;
  unsigned short* qbf = ctx;  // alias: qbf consumed by inproj before attn writes ctx
  const size_t NEED_FULL = 32 + (3145728L + 1048576L + 4L * 8388608L + 16777216L) * 2;
  const bool big = ws_size >= NEED_FULL;

  detect_kernel<<<dim3(1), dim3(64), 0, stream>>>((const unsigned int*)query, flag);
  if (big)
    convert_bf16<<<dim3(8192), dim3(256), 0, stream>>>(rpb, rpbbf, flag);
  convert_q<<<dim3(4096), dim3(256), 0, stream>>>(query, qbf, flag);
  eff_weights<<<dim3(12288), dim3(256), 0, stream>>>(ipw, il, ir, w_in_eff, flag);
  eff_weights<<<dim3(4096), dim3(256), 0, stream>>>(opw, ol, orr, w_out_eff, flag);
  inproj_kernel<<<dim3(24, 64), dim3(256), 0, stream>>>(qbf, w_in_eff, ipb, qh, kh, vt, flag);
  attn_kernel<<<dim3(16, 128), dim3(256), 0, stream>>>(qh, kh, vt, rpb,
                                                       big ? rpbbf : nullptr, ctx, flag);
  outproj_kernel<<<dim3(8, 64), dim3(256), 0, stream>>>(ctx, w_out_eff, opb, d_out, flag);
}

// Round 6
// 405.790 us; speedup vs baseline: 1.0861x; 1.0292x over previous
//
#include <hip/hip_runtime.h>
#include <hip/hip_bf16.h>

// Problem dims (fixed): T=1024 B=8 E=1024 H=16 hd=64 R=16, M=T*B=8192, F=3*E=3072
// Inputs f32 (runtime-detected; bf16 fallback). Intermediates bf16, fp32 accum.

typedef __attribute__((ext_vector_type(8))) __bf16 bf16x8;
typedef __attribute__((ext_vector_type(4))) float f32x4;

__device__ __forceinline__ float bf2f(unsigned short u) {
  union { unsigned int i; float f; } v; v.i = ((unsigned int)u) << 16; return v.f;
}
__device__ __forceinline__ unsigned short f2bf(float f) {
  union { float f; unsigned int i; } v; v.f = f;
  unsigned int x = v.i;
  unsigned int r = x + 0x7FFFu + ((x >> 16) & 1u);
  return (unsigned short)(r >> 16);
}
__device__ __forceinline__ unsigned int pack2(float a, float b) {
  return (unsigned int)f2bf(a) | ((unsigned int)f2bf(b) << 16);
}
__device__ __forceinline__ float ld_in(const void* p, long idx, int isf32) {
  if (isf32) return ((const float*)p)[idx];
  return bf2f(((const unsigned short*)p)[idx]);
}
// async global->LDS, 16 B per lane; LDS dst = wave-uniform base + lane*16
__device__ __forceinline__ void gl_lds16(const unsigned short* g, unsigned short* l) {
  __builtin_amdgcn_global_load_lds(
      (const __attribute__((address_space(1))) unsigned int*)g,
      (__attribute__((address_space(3))) unsigned int*)l, 16, 0, 0);
}

// ---------------------------------------------------------------------------
// Kernel 0: dtype detector (f32-stored vs bf16-packed).
__global__ void detect_kernel(const unsigned int* __restrict__ q, int* __restrict__ flag) {
  __shared__ int cnt;
  if (threadIdx.x == 0) cnt = 0;
  __syncthreads();
  unsigned int w = q[threadIdx.x];
  int c = 0;
  if (((w >> 7) & 0xFFu) >= 0xC0u) c++;
  if (((w >> 23) & 0xFFu) >= 0xC0u) c++;
  atomicAdd(&cnt, c);
  __syncthreads();
  if (threadIdx.x == 0) flag[0] = (cnt >= 2) ? 1 : 0;
}

// ---------------------------------------------------------------------------
// Kernel 0b: any f32 buffer -> bf16 (8 elems/thread). If !isf32, plain copy.
__global__ __launch_bounds__(256) void convert_bf16(
    const void* __restrict__ in, unsigned short* __restrict__ out,
    const int* __restrict__ flag) {
  long idx = ((long)blockIdx.x * 256 + threadIdx.x) * 8;
  if (flag[0]) {
    const float* p = (const float*)in + idx;
    float4 a = ((const float4*)p)[0], b = ((const float4*)p)[1];
    uint4 v;
    v.x = pack2(a.x, a.y); v.y = pack2(a.z, a.w);
    v.z = pack2(b.x, b.y); v.w = pack2(b.z, b.w);
    *(uint4*)(out + idx) = v;
  } else {
    *(uint4*)(out + idx) = *(const uint4*)((const unsigned short*)in + idx);
  }
}

// ---------------------------------------------------------------------------
// Kernel 0c: query convert with row permutation (T,B,E) -> (B,T,E).
// Row in = t*8+b (2KB contiguous), row out = b*1024+t. Pure row permute:
// both sides stay 16B-chunk contiguous within a row. Makes b uniform per
// 128-row inproj tile and t contiguous -> vectorizable v^T epilogue stores.
__global__ __launch_bounds__(256) void convert_q(
    const void* __restrict__ in, unsigned short* __restrict__ out,
    const int* __restrict__ flag) {
  long idx = ((long)blockIdx.x * 256 + threadIdx.x) * 8;
  const int inrow = (int)(idx >> 10);
  const int e = (int)(idx & 1023);
  const long oidx = ((long)((inrow & 7) << 10 | (inrow >> 3))) * 1024 + e;
  if (flag[0]) {
    const float* p = (const float*)in + idx;
    float4 a = ((const float4*)p)[0], b = ((const float4*)p)[1];
    uint4 v;
    v.x = pack2(a.x, a.y); v.y = pack2(a.z, a.w);
    v.z = pack2(b.x, b.y); v.w = pack2(b.z, b.w);
    *(uint4*)(out + oidx) = v;
  } else {
    *(uint4*)(out + oidx) = *(const uint4*)((const unsigned short*)in + idx);
  }
}

// ---------------------------------------------------------------------------
// Kernel 1: W_eff = W + left @ right (rank-16), bf16 out.
__global__ __launch_bounds__(256) void eff_weights(
    const void* __restrict__ w, const void* __restrict__ left,
    const void* __restrict__ right, unsigned short* __restrict__ outw,
    const int* __restrict__ flag) {
  const int isf32 = flag[0];
  long idx = (long)blockIdx.x * 256 + threadIdx.x;
  long f = idx >> 10, e = idx & 1023;
  float acc = ld_in(w, idx, isf32);
#pragma unroll
  for (int r = 0; r < 16; ++r)
    acc += ld_in(left, (f << 4) + r, isf32) * ld_in(right, (r << 10) + e, isf32);
  outw[idx] = f2bf(acc);
}

// ---------------------------------------------------------------------------
// Kernel 2: in-proj GEMM, 128x128 tile, 1-phase global_load_lds staging.
// v5: BK=64 (was 32) — barrier amortization. Per-barrier MFMA doubled
// (16 -> 32) against the same vmcnt(0) drain; barrier count halved (32->16).
// K-tile stored as two independent [128][32] halves at +4096-short offset:
// LDS addressing/bank profile of each ds_read_b128 identical to the proven
// BK=32 layout; gl_lds dests stay contiguous per 16-row chunk. LDS 32 KB ->
// LDS-limit 5 blocks/CU; VGPR(~104) already limits to 4 — occupancy flat.
// (R4 lesson: do NOT graft 2-phase dbuf here — regressed 124->155 us.)
// A rows are (b,t) layout: m = b*1024+t. Epilogue: q*0.125, k scalar 32B-seg
// stores; v^T as ushort4 (16x32B segments per instr).
__global__ __launch_bounds__(256) void inproj_kernel(
    const unsigned short* __restrict__ qbf,    // (8,1024,1024) bf16, row=b*1024+t
    const unsigned short* __restrict__ weff,   // (3072,1024) bf16
    const void* __restrict__ bias,             // (3072)
    unsigned short* __restrict__ qh, unsigned short* __restrict__ kh,
    unsigned short* __restrict__ vt, const int* __restrict__ flag) {
  __shared__ __align__(16) unsigned short As[2 * 128 * 32];  // [kk][row][32]
  __shared__ __align__(16) unsigned short Bs[2 * 128 * 32];
  const int isf32 = flag[0];
  const int tid = threadIdx.x;
  const int wave = tid >> 6, lane = tid & 63, quad = lane >> 4, lrow = lane & 15;
  const int wr0 = (wave >> 1) * 64, wc0 = (wave & 1) * 64;
  const int fbase = blockIdx.x * 128, mbase = blockIdx.y * 128;
  // staging: wave covers rows [32w,32w+16) and [32w+16,32w+32) of both K-halves;
  // lane covers row 32w+16i+(lane>>2), cols (lane&3)*8..+8 (16B/lane, contig LDS)
  const int srow = lane >> 2, scol = (lane & 3) * 8;
  const unsigned short* ag  = qbf  + (long)(mbase + 32 * wave + srow) * 1024 + scol;
  const unsigned short* ag2 = ag + 16 * 1024;
  const unsigned short* bg  = weff + (long)(fbase + 32 * wave + srow) * 1024 + scol;
  const unsigned short* bg2 = bg + 16 * 1024;
  unsigned short* la  = &As[(32 * wave) * 32];
  unsigned short* la2 = &As[(32 * wave + 16) * 32];
  unsigned short* lb  = &Bs[(32 * wave) * 32];
  unsigned short* lb2 = &Bs[(32 * wave + 16) * 32];

  f32x4 acc[4][4] = {};
  for (int k0 = 0; k0 < 1024; k0 += 64) {
    gl_lds16(ag + k0, la);
    gl_lds16(ag2 + k0, la2);
    gl_lds16(ag + k0 + 32, la + 4096);
    gl_lds16(ag2 + k0 + 32, la2 + 4096);
    gl_lds16(bg + k0, lb);
    gl_lds16(bg2 + k0, lb2);
    gl_lds16(bg + k0 + 32, lb + 4096);
    gl_lds16(bg2 + k0 + 32, lb2 + 4096);
    __syncthreads();             // drains vmcnt: staged data visible
#pragma unroll
    for (int kk = 0; kk < 2; ++kk) {
      bf16x8 af[4], bfv[4];
#pragma unroll
      for (int mi = 0; mi < 4; ++mi)
        af[mi] = *(const bf16x8*)&As[kk * 4096 + (wr0 + mi * 16 + lrow) * 32 + quad * 8];
#pragma unroll
      for (int ni = 0; ni < 4; ++ni)
        bfv[ni] = *(const bf16x8*)&Bs[kk * 4096 + (wc0 + ni * 16 + lrow) * 32 + quad * 8];
#pragma unroll
      for (int mi = 0; mi < 4; ++mi)
#pragma unroll
        for (int ni = 0; ni < 4; ++ni)
          acc[mi][ni] = __builtin_amdgcn_mfma_f32_16x16x32_bf16(af[mi], bfv[ni], acc[mi][ni], 0, 0, 0);
    }
    __syncthreads();             // protect LDS before next stage
  }
  const int which = fbase >> 10;               // 0=q 1=k 2=v (uniform per block)
  const int h = ((fbase + wc0) >> 6) & 15;     // wave's 64 cols = one head
  const int bq = mbase >> 10;                  // uniform batch index per block
  const int tbase = (mbase & 1023) + wr0;
#pragma unroll
  for (int ni = 0; ni < 4; ++ni) {
    const int d = ni * 16 + lrow;
    const float bv = ld_in(bias, fbase + wc0 + d, isf32);
    if (which == 2) {
      unsigned short* vrow = vt + ((long)(bq * 16 + h) * 64 + d) * 1024;
#pragma unroll
      for (int mi = 0; mi < 4; ++mi) {
        const int t = tbase + mi * 16 + quad * 4;
        ushort4 v;
        v.x = f2bf(acc[mi][ni][0] + bv);
        v.y = f2bf(acc[mi][ni][1] + bv);
        v.z = f2bf(acc[mi][ni][2] + bv);
        v.w = f2bf(acc[mi][ni][3] + bv);
        *(ushort4*)(vrow + t) = v;
      }
    } else {
      unsigned short* qk = (which == 0) ? qh : kh;
      const float sc = (which == 0) ? 0.125f : 1.0f;
      unsigned short* row0 = qk + (long)(bq * 16 + h) * 65536;
#pragma unroll
      for (int mi = 0; mi < 4; ++mi)
#pragma unroll
        for (int r = 0; r < 4; ++r) {
          const int t = tbase + mi * 16 + quad * 4 + r;
          row0[(long)t * 64 + d] = f2bf((acc[mi][ni][r] + bv) * sc);
        }
    }
  }
}

// ---------------------------------------------------------------------------
// Kernel 3: attention per (b,h, 64-row q-tile); s-tiles of 64.
// (unchanged: 2-phase K/V dbuf via global_load_lds, register bias prefetch,
// swizzled Ps — R3-verified, no longer top-5.)
__global__ __launch_bounds__(256) void attn_kernel(
    const unsigned short* __restrict__ qh, const unsigned short* __restrict__ kh,
    const unsigned short* __restrict__ vt, const void* __restrict__ rpb,
    const unsigned short* __restrict__ pre,  // bf16 bias copy or nullptr
    unsigned short* __restrict__ ctx, const int* __restrict__ flag) {
  __shared__ __align__(16) unsigned short Ks[2][4096];  // [buf][kk*2048 + s*32 + d']
  __shared__ __align__(16) unsigned short Vs[2][4096];  // [buf][kk*2048 + d*32 + s']
  __shared__ __align__(16) unsigned short Ps[4][1024];  // [wave][swizzled row*64+col]
  const int isf32 = flag[0];
  const int tid = threadIdx.x;
  const int wave = tid >> 6, lane = tid & 63, quad = lane >> 4, lrow = lane & 15;
  const int b = blockIdx.y & 7, h = blockIdx.y >> 3, bh = b * 16 + h;
  const int t0 = blockIdx.x * 64;

  const unsigned short* qbase = qh + ((long)(bh * 1024) + t0 + wave * 16 + lrow) * 64;
  bf16x8 qf0 = *(const bf16x8*)(qbase + quad * 8);
  bf16x8 qf1 = *(const bf16x8*)(qbase + 32 + quad * 8);

  const unsigned short* kbase = kh + (long)bh * 65536;
  const unsigned short* vbase = vt + (long)bh * 65536;

  // bias element (r,n) at s-tile s0: bidx0 + r*1024 + s0 + n*16
  const long bidx0 = ((long)h * 1024 + t0 + wave * 16 + quad * 4) * 1024 + lrow;
  const unsigned short* bs16 = pre ? pre : (const unsigned short*)rpb;
  const bool bf32 = (isf32 && pre == nullptr);
  const float* bsf = (const float*)rpb;

  // staging: wave issues jobs j=2w,2w+1 for BOTH K and V.
  // j -> kk=j>>2 (32-col half), ii=j&3 (16-row chunk). K rows = s (stride 64),
  // V rows = d (stride 1024; cols t contiguous -> 16-segment coalesced).
  const int j0 = 2 * wave, j1 = j0 + 1;
  const int kk0 = j0 >> 2, ii0 = j0 & 3, kk1 = j1 >> 2, ii1 = j1 & 3;
  const int sr = lane >> 2, sc = (lane & 3) * 8;
  const unsigned short* kg0 = kbase + (long)(16 * ii0 + sr) * 64 + kk0 * 32 + sc;
  const unsigned short* kg1 = kbase + (long)(16 * ii1 + sr) * 64 + kk1 * 32 + sc;
  const unsigned short* vg0 = vbase + (long)(16 * ii0 + sr) * 1024 + kk0 * 32 + sc;
  const unsigned short* vg1 = vbase + (long)(16 * ii1 + sr) * 1024 + kk1 * 32 + sc;
  const int lo0 = kk0 * 2048 + ii0 * 512, lo1 = kk1 * 2048 + ii1 * 512;

  f32x4 oacc[4] = {};
  float rsum[4] = {0.f, 0.f, 0.f, 0.f};
  unsigned int bcur[4][4], bnxt[4][4];

  // prologue: stage tile 0 (K+V) and load bias(0); barrier drains vmcnt.
  gl_lds16(kg0, &Ks[0][lo0]);
  gl_lds16(kg1, &Ks[0][lo1]);
  gl_lds16(vg0, &Vs[0][lo0]);
  gl_lds16(vg1, &Vs[0][lo1]);
  if (bf32) {
#pragma unroll
    for (int r = 0; r < 4; ++r)
#pragma unroll
      for (int n = 0; n < 4; ++n)
        bcur[r][n] = __float_as_uint(bsf[bidx0 + r * 1024 + n * 16]);
  } else {
#pragma unroll
    for (int r = 0; r < 4; ++r)
#pragma unroll
      for (int n = 0; n < 4; ++n)
        bcur[r][n] = (unsigned int)bs16[bidx0 + r * 1024 + n * 16];
  }
  __syncthreads();

  for (int t = 0; t < 16; ++t) {
    const int cur = t & 1;
    const int s0 = t << 6;
    if (t < 15) {            // prefetch next tile: K,V -> LDS buf^1, bias -> regs
      const int sn = s0 + 64;
      gl_lds16(kg0 + (long)sn * 64, &Ks[cur ^ 1][lo0]);
      gl_lds16(kg1 + (long)sn * 64, &Ks[cur ^ 1][lo1]);
      gl_lds16(vg0 + sn, &Vs[cur ^ 1][lo0]);
      gl_lds16(vg1 + sn, &Vs[cur ^ 1][lo1]);
      if (bf32) {
#pragma unroll
        for (int r = 0; r < 4; ++r)
#pragma unroll
          for (int n = 0; n < 4; ++n)
            bnxt[r][n] = __float_as_uint(bsf[bidx0 + r * 1024 + sn + n * 16]);
      } else {
#pragma unroll
        for (int r = 0; r < 4; ++r)
#pragma unroll
          for (int n = 0; n < 4; ++n)
            bnxt[r][n] = (unsigned int)bs16[bidx0 + r * 1024 + sn + n * 16];
      }
    }

    f32x4 sacc[4] = {};
#pragma unroll
    for (int n = 0; n < 4; ++n) {
      bf16x8 kf0 = *(const bf16x8*)&Ks[cur][(n * 16 + lrow) * 32 + quad * 8];
      bf16x8 kf1 = *(const bf16x8*)&Ks[cur][2048 + (n * 16 + lrow) * 32 + quad * 8];
      sacc[n] = __builtin_amdgcn_mfma_f32_16x16x32_bf16(qf0, kf0, sacc[n], 0, 0, 0);
      sacc[n] = __builtin_amdgcn_mfma_f32_16x16x32_bf16(qf1, kf1, sacc[n], 0, 0, 0);
    }

#pragma unroll
    for (int n = 0; n < 4; ++n)
#pragma unroll
      for (int r = 0; r < 4; ++r) {
        const int row = quad * 4 + r;
        const float bv = bf32 ? __uint_as_float(bcur[r][n])
                              : bf2f((unsigned short)bcur[r][n]);
        const float p = __expf(sacc[n][r] + bv);
        rsum[r] += p;
        Ps[wave][(row * 64 + n * 16 + lrow) ^ ((row & 7) << 3)] = f2bf(p);
      }

    asm volatile("s_waitcnt lgkmcnt(0)" ::: "memory");  // Ps writes visible (same wave)

#pragma unroll
    for (int kk = 0; kk < 2; ++kk) {
      bf16x8 pf = *(const bf16x8*)&Ps[wave][(lrow * 64 + kk * 32 + quad * 8) ^ ((lrow & 7) << 3)];
#pragma unroll
      for (int n = 0; n < 4; ++n) {
        bf16x8 vf = *(const bf16x8*)&Vs[cur][kk * 2048 + (n * 16 + lrow) * 32 + quad * 8];
        oacc[n] = __builtin_amdgcn_mfma_f32_16x16x32_bf16(pf, vf, oacc[n], 0, 0, 0);
      }
    }
    __syncthreads();   // vmcnt(0): next-tile stage landed; WAR fence for buf flip
    if (t < 15) {
#pragma unroll
      for (int r = 0; r < 4; ++r)
#pragma unroll
        for (int n = 0; n < 4; ++n) bcur[r][n] = bnxt[r][n];
    }
  }

  // single deferred reduction: sum over the 16 lanes (lrow) sharing this quad
#pragma unroll
  for (int msk = 1; msk <= 8; msk <<= 1)
#pragma unroll
    for (int r = 0; r < 4; ++r)
      rsum[r] += __shfl_xor(rsum[r], msk, 64);

  float linv[4];
#pragma unroll
  for (int r = 0; r < 4; ++r) linv[r] = 1.0f / rsum[r];
#pragma unroll
  for (int n = 0; n < 4; ++n)
#pragma unroll
    for (int r = 0; r < 4; ++r) {
      const int t = t0 + wave * 16 + quad * 4 + r;
      ctx[((long)t * 8 + b) * 1024 + h * 64 + n * 16 + lrow] = f2bf(oacc[n][r] * linv[r]);
    }
}

// ---------------------------------------------------------------------------
// Kernel 4: out-proj GEMM, 128x128 tile, 1-phase staging; v5: BK=64 (same
// barrier-amortization change as inproj, two [128][32] K-halves).
__global__ __launch_bounds__(256) void outproj_kernel(
    const unsigned short* __restrict__ ctx, const unsigned short* __restrict__ weff,
    const void* __restrict__ bias, void* __restrict__ out,
    const int* __restrict__ flag) {
  __shared__ __align__(16) unsigned short As[2 * 128 * 32];
  __shared__ __align__(16) unsigned short Bs[2 * 128 * 32];
  const int isf32 = flag[0];
  const int tid = threadIdx.x;
  const int wave = tid >> 6, lane = tid & 63, quad = lane >> 4, lrow = lane & 15;
  const int wr0 = (wave >> 1) * 64, wc0 = (wave & 1) * 64;
  const int fbase = blockIdx.x * 128, mbase = blockIdx.y * 128;
  const int srow = lane >> 2, scol = (lane & 3) * 8;
  const unsigned short* ag  = ctx  + (long)(mbase + 32 * wave + srow) * 1024 + scol;
  const unsigned short* ag2 = ag + 16 * 1024;
  const unsigned short* bg  = weff + (long)(fbase + 32 * wave + srow) * 1024 + scol;
  const unsigned short* bg2 = bg + 16 * 1024;
  unsigned short* la  = &As[(32 * wave) * 32];
  unsigned short* la2 = &As[(32 * wave + 16) * 32];
  unsigned short* lb  = &Bs[(32 * wave) * 32];
  unsigned short* lb2 = &Bs[(32 * wave + 16) * 32];

  f32x4 acc[4][4] = {};
  for (int k0 = 0; k0 < 1024; k0 += 64) {
    gl_lds16(ag + k0, la);
    gl_lds16(ag2 + k0, la2);
    gl_lds16(ag + k0 + 32, la + 4096);
    gl_lds16(ag2 + k0 + 32, la2 + 4096);
    gl_lds16(bg + k0, lb);
    gl_lds16(bg2 + k0, lb2);
    gl_lds16(bg + k0 + 32, lb + 4096);
    gl_lds16(bg2 + k0 + 32, lb2 + 4096);
    __syncthreads();
#pragma unroll
    for (int kk = 0; kk < 2; ++kk) {
      bf16x8 af[4], bfv[4];
#pragma unroll
      for (int mi = 0; mi < 4; ++mi)
        af[mi] = *(const bf16x8*)&As[kk * 4096 + (wr0 + mi * 16 + lrow) * 32 + quad * 8];
#pragma unroll
      for (int ni = 0; ni < 4; ++ni)
        bfv[ni] = *(const bf16x8*)&Bs[kk * 4096 + (wc0 + ni * 16 + lrow) * 32 + quad * 8];
#pragma unroll
      for (int mi = 0; mi < 4; ++mi)
#pragma unroll
        for (int ni = 0; ni < 4; ++ni)
          acc[mi][ni] = __builtin_amdgcn_mfma_f32_16x16x32_bf16(af[mi], bfv[ni], acc[mi][ni], 0, 0, 0);
    }
    __syncthreads();
  }
#pragma unroll
  for (int ni = 0; ni < 4; ++ni) {
    const int f = fbase + wc0 + ni * 16 + lrow;
    const float bv = ld_in(bias, f, isf32);
#pragma unroll
    for (int mi = 0; mi < 4; ++mi)
#pragma unroll
      for (int r = 0; r < 4; ++r) {
        const int m = mbase + wr0 + mi * 16 + quad * 4 + r;
        const float val = acc[mi][ni][r] + bv;
        if (isf32) ((float*)out)[(long)m * 1024 + f] = val;
        else       ((unsigned short*)out)[(long)m * 1024 + f] = f2bf(val);
      }
  }
}

// ---------------------------------------------------------------------------
extern "C" void kernel_launch(void* const* d_in, const int* in_sizes, int n_in,
                              void* d_out, int out_size, void* d_ws, size_t ws_size,
                              hipStream_t stream) {
  (void)out_size;
  static const int EXP[10] = {8388608, 3145728, 3072, 49152, 16384,
                              1048576, 1024, 16384, 16384, 16777216};
  if (n_in != 10) return;
  for (int i = 0; i < 10; ++i) if (in_sizes[i] != EXP[i]) return;

  const void* query = d_in[0];
  const void* ipw = d_in[1];  const void* ipb = d_in[2];
  const void* il  = d_in[3];  const void* ir  = d_in[4];
  const void* opw = d_in[5];  const void* opb = d_in[6];
  const void* ol  = d_in[7];  const void* orr = d_in[8];
  const void* rpb = d_in[9];

  // ws: flag | W_in_eff 3072x1024 | W_out_eff 1024x1024 | q | k | vT | ctx
  //     (each 8192x1024) | rpb_bf16 16M.  qbf aliases ctx (dead until attn).
  int* flag = (int*)d_ws;
  unsigned short* base = (unsigned short*)d_ws + 16;
  unsigned short* w_in_eff  = base;
  unsigned short* w_out_eff = w_in_eff + (long)3072 * 1024;
  unsigned short* qh  = w_out_eff + (long)1024 * 1024;
  unsigned short* kh  = qh + 8388608L;
  unsigned short* vt  = kh + 8388608L;
  unsigned short* ctx = vt + 8388608L;
  unsigned short* rpbbf = ctx + 8388608L;
  unsigned short* qbf = ctx;  // alias: qbf consumed by inproj before attn writes ctx
  const size_t NEED_FULL = 32 + (3145728L + 1048576L + 4L * 8388608L + 16777216L) * 2;
  const bool big = ws_size >= NEED_FULL;

  detect_kernel<<<dim3(1), dim3(64), 0, stream>>>((const unsigned int*)query, flag);
  if (big)
    convert_bf16<<<dim3(8192), dim3(256), 0, stream>>>(rpb, rpbbf, flag);
  convert_q<<<dim3(4096), dim3(256), 0, stream>>>(query, qbf, flag);
  eff_weights<<<dim3(12288), dim3(256), 0, stream>>>(ipw, il, ir, w_in_eff, flag);
  eff_weights<<<dim3(4096), dim3(256), 0, stream>>>(opw, ol, orr, w_out_eff, flag);
  inproj_kernel<<<dim3(24, 64), dim3(256), 0, stream>>>(qbf, w_in_eff, ipb, qh, kh, vt, flag);
  attn_kernel<<<dim3(16, 128), dim3(256), 0, stream>>>(qh, kh, vt, rpb,
                                                       big ? rpbbf : nullptr, ctx, flag);
  outproj_kernel<<<dim3(8, 64), dim3(256), 0, stream>>>(ctx, w_out_eff, opb, d_out, flag);
}

// Round 7
// 400.686 us; speedup vs baseline: 1.0999x; 1.0127x over previous
//
#include <hip/hip_runtime.h>
#include <hip/hip_bf16.h>

// Problem dims (fixed): T=1024 B=8 E=1024 H=16 hd=64 R=16, M=T*B=8192, F=3*E=3072
// Inputs f32 (runtime-detected; bf16 fallback). Intermediates bf16, fp32 accum.
// exp2 trick: Q pre-scaled by 0.125*log2e, bias bf16 copy pre-scaled by log2e,
// so softmax uses raw v_exp_f32 (2^x) with no per-element multiply.

typedef __attribute__((ext_vector_type(8))) __bf16 bf16x8;
typedef __attribute__((ext_vector_type(4))) float f32x4;

#define LOG2E 1.44269504f

__device__ __forceinline__ float bf2f(unsigned short u) {
  union { unsigned int i; float f; } v; v.i = ((unsigned int)u) << 16; return v.f;
}
__device__ __forceinline__ unsigned short f2bf(float f) {
  union { float f; unsigned int i; } v; v.f = f;
  unsigned int x = v.i;
  unsigned int r = x + 0x7FFFu + ((x >> 16) & 1u);
  return (unsigned short)(r >> 16);
}
__device__ __forceinline__ unsigned int pack2(float a, float b) {
  return (unsigned int)f2bf(a) | ((unsigned int)f2bf(b) << 16);
}
__device__ __forceinline__ float ld_in(const void* p, long idx, int isf32) {
  if (isf32) return ((const float*)p)[idx];
  return bf2f(((const unsigned short*)p)[idx]);
}
__device__ __forceinline__ float fexp2(float x) {
#if __has_builtin(__builtin_amdgcn_exp2f)
  return __builtin_amdgcn_exp2f(x);
#else
  return __expf(x * 0.69314718056f);
#endif
}
// async global->LDS, 16 B per lane; LDS dst = wave-uniform base + lane*16
__device__ __forceinline__ void gl_lds16(const unsigned short* g, unsigned short* l) {
  __builtin_amdgcn_global_load_lds(
      (const __attribute__((address_space(1))) unsigned int*)g,
      (__attribute__((address_space(3))) unsigned int*)l, 16, 0, 0);
}

// ---------------------------------------------------------------------------
// Kernel 0: dtype detector (f32-stored vs bf16-packed).
__global__ void detect_kernel(const unsigned int* __restrict__ q, int* __restrict__ flag) {
  __shared__ int cnt;
  if (threadIdx.x == 0) cnt = 0;
  __syncthreads();
  unsigned int w = q[threadIdx.x];
  int c = 0;
  if (((w >> 7) & 0xFFu) >= 0xC0u) c++;
  if (((w >> 23) & 0xFFu) >= 0xC0u) c++;
  atomicAdd(&cnt, c);
  __syncthreads();
  if (threadIdx.x == 0) flag[0] = (cnt >= 2) ? 1 : 0;
}

// ---------------------------------------------------------------------------
// Kernel 0b: bias -> bf16 PRE-SCALED by log2e (8 elems/thread).
__global__ __launch_bounds__(256) void convert_bias(
    const void* __restrict__ in, unsigned short* __restrict__ out,
    const int* __restrict__ flag) {
  long idx = ((long)blockIdx.x * 256 + threadIdx.x) * 8;
  if (flag[0]) {
    const float* p = (const float*)in + idx;
    float4 a = ((const float4*)p)[0], b = ((const float4*)p)[1];
    uint4 v;
    v.x = pack2(a.x * LOG2E, a.y * LOG2E); v.y = pack2(a.z * LOG2E, a.w * LOG2E);
    v.z = pack2(b.x * LOG2E, b.y * LOG2E); v.w = pack2(b.z * LOG2E, b.w * LOG2E);
    *(uint4*)(out + idx) = v;
  } else {
    const unsigned short* p = (const unsigned short*)in + idx;
    unsigned short s[8];
#pragma unroll
    for (int i = 0; i < 8; ++i) s[i] = f2bf(bf2f(p[i]) * LOG2E);
    uint4 v;
    v.x = (unsigned int)s[0] | ((unsigned int)s[1] << 16);
    v.y = (unsigned int)s[2] | ((unsigned int)s[3] << 16);
    v.z = (unsigned int)s[4] | ((unsigned int)s[5] << 16);
    v.w = (unsigned int)s[6] | ((unsigned int)s[7] << 16);
    *(uint4*)(out + idx) = v;
  }
}

// ---------------------------------------------------------------------------
// Kernel 0c: query convert with row permutation (T,B,E) -> (B,T,E).
// Row in = t*8+b (2KB contiguous), row out = b*1024+t. Pure row permute:
// both sides stay 16B-chunk contiguous within a row. Makes b uniform per
// 128-row inproj tile and t contiguous -> vectorizable v^T epilogue stores.
__global__ __launch_bounds__(256) void convert_q(
    const void* __restrict__ in, unsigned short* __restrict__ out,
    const int* __restrict__ flag) {
  long idx = ((long)blockIdx.x * 256 + threadIdx.x) * 8;
  const int inrow = (int)(idx >> 10);
  const int e = (int)(idx & 1023);
  const long oidx = ((long)((inrow & 7) << 10 | (inrow >> 3))) * 1024 + e;
  if (flag[0]) {
    const float* p = (const float*)in + idx;
    float4 a = ((const float4*)p)[0], b = ((const float4*)p)[1];
    uint4 v;
    v.x = pack2(a.x, a.y); v.y = pack2(a.z, a.w);
    v.z = pack2(b.x, b.y); v.w = pack2(b.z, b.w);
    *(uint4*)(out + oidx) = v;
  } else {
    *(uint4*)(out + oidx) = *(const uint4*)((const unsigned short*)in + idx);
  }
}

// ---------------------------------------------------------------------------
// Kernel 1: W_eff = W + left @ right (rank-16), bf16 out.
__global__ __launch_bounds__(256) void eff_weights(
    const void* __restrict__ w, const void* __restrict__ left,
    const void* __restrict__ right, unsigned short* __restrict__ outw,
    const int* __restrict__ flag) {
  const int isf32 = flag[0];
  long idx = (long)blockIdx.x * 256 + threadIdx.x;
  long f = idx >> 10, e = idx & 1023;
  float acc = ld_in(w, idx, isf32);
#pragma unroll
  for (int r = 0; r < 16; ++r)
    acc += ld_in(left, (f << 4) + r, isf32) * ld_in(right, (r << 10) + e, isf32);
  outw[idx] = f2bf(acc);
}

// ---------------------------------------------------------------------------
// Kernel 2: in-proj GEMM, 128x128 tile, BK=64, 1-phase global_load_lds
// staging (R5-verified; R4 lesson: no 2-phase dbuf graft here).
// K-tile = two independent [128][32] halves at +4096-short offset.
// q epilogue scale = 0.125*log2e (exp2 trick).
__global__ __launch_bounds__(256) void inproj_kernel(
    const unsigned short* __restrict__ qbf,    // (8,1024,1024) bf16, row=b*1024+t
    const unsigned short* __restrict__ weff,   // (3072,1024) bf16
    const void* __restrict__ bias,             // (3072)
    unsigned short* __restrict__ qh, unsigned short* __restrict__ kh,
    unsigned short* __restrict__ vt, const int* __restrict__ flag) {
  __shared__ __align__(16) unsigned short As[2 * 128 * 32];  // [kk][row][32]
  __shared__ __align__(16) unsigned short Bs[2 * 128 * 32];
  const int isf32 = flag[0];
  const int tid = threadIdx.x;
  const int wave = tid >> 6, lane = tid & 63, quad = lane >> 4, lrow = lane & 15;
  const int wr0 = (wave >> 1) * 64, wc0 = (wave & 1) * 64;
  const int fbase = blockIdx.x * 128, mbase = blockIdx.y * 128;
  const int srow = lane >> 2, scol = (lane & 3) * 8;
  const unsigned short* ag  = qbf  + (long)(mbase + 32 * wave + srow) * 1024 + scol;
  const unsigned short* ag2 = ag + 16 * 1024;
  const unsigned short* bg  = weff + (long)(fbase + 32 * wave + srow) * 1024 + scol;
  const unsigned short* bg2 = bg + 16 * 1024;
  unsigned short* la  = &As[(32 * wave) * 32];
  unsigned short* la2 = &As[(32 * wave + 16) * 32];
  unsigned short* lb  = &Bs[(32 * wave) * 32];
  unsigned short* lb2 = &Bs[(32 * wave + 16) * 32];

  f32x4 acc[4][4] = {};
  for (int k0 = 0; k0 < 1024; k0 += 64) {
    gl_lds16(ag + k0, la);
    gl_lds16(ag2 + k0, la2);
    gl_lds16(ag + k0 + 32, la + 4096);
    gl_lds16(ag2 + k0 + 32, la2 + 4096);
    gl_lds16(bg + k0, lb);
    gl_lds16(bg2 + k0, lb2);
    gl_lds16(bg + k0 + 32, lb + 4096);
    gl_lds16(bg2 + k0 + 32, lb2 + 4096);
    __syncthreads();             // drains vmcnt: staged data visible
#pragma unroll
    for (int kk = 0; kk < 2; ++kk) {
      bf16x8 af[4], bfv[4];
#pragma unroll
      for (int mi = 0; mi < 4; ++mi)
        af[mi] = *(const bf16x8*)&As[kk * 4096 + (wr0 + mi * 16 + lrow) * 32 + quad * 8];
#pragma unroll
      for (int ni = 0; ni < 4; ++ni)
        bfv[ni] = *(const bf16x8*)&Bs[kk * 4096 + (wc0 + ni * 16 + lrow) * 32 + quad * 8];
#pragma unroll
      for (int mi = 0; mi < 4; ++mi)
#pragma unroll
        for (int ni = 0; ni < 4; ++ni)
          acc[mi][ni] = __builtin_amdgcn_mfma_f32_16x16x32_bf16(af[mi], bfv[ni], acc[mi][ni], 0, 0, 0);
    }
    __syncthreads();             // protect LDS before next stage
  }
  const int which = fbase >> 10;               // 0=q 1=k 2=v (uniform per block)
  const int h = ((fbase + wc0) >> 6) & 15;     // wave's 64 cols = one head
  const int bq = mbase >> 10;                  // uniform batch index per block
  const int tbase = (mbase & 1023) + wr0;
#pragma unroll
  for (int ni = 0; ni < 4; ++ni) {
    const int d = ni * 16 + lrow;
    const float bv = ld_in(bias, fbase + wc0 + d, isf32);
    if (which == 2) {
      unsigned short* vrow = vt + ((long)(bq * 16 + h) * 64 + d) * 1024;
#pragma unroll
      for (int mi = 0; mi < 4; ++mi) {
        const int t = tbase + mi * 16 + quad * 4;
        ushort4 v;
        v.x = f2bf(acc[mi][ni][0] + bv);
        v.y = f2bf(acc[mi][ni][1] + bv);
        v.z = f2bf(acc[mi][ni][2] + bv);
        v.w = f2bf(acc[mi][ni][3] + bv);
        *(ushort4*)(vrow + t) = v;
      }
    } else {
      unsigned short* qk = (which == 0) ? qh : kh;
      const float sc = (which == 0) ? (0.125f * LOG2E) : 1.0f;
      unsigned short* row0 = qk + (long)(bq * 16 + h) * 65536;
#pragma unroll
      for (int mi = 0; mi < 4; ++mi)
#pragma unroll
        for (int r = 0; r < 4; ++r) {
          const int t = tbase + mi * 16 + quad * 4 + r;
          row0[(long)t * 64 + d] = f2bf((acc[mi][ni][r] + bv) * sc);
        }
    }
  }
}

// ---------------------------------------------------------------------------
// Kernel 3: attention per (b,h, 64-row q-tile); s-tiles of 64.
// v6: VALU-thinned softmax (was VALUBusy 49%, MfmaUtil 14% — conversion-strip
// bound): p = v_exp_f32(S'+B') directly (inputs pre-scaled by log2e), and
// P->bf16 via v_cvt_pk_bf16_f32 pairs (T12 recipe; hi half folds to
// ds_write_b16_d16_hi). ~160 -> ~95 VALU ops/iter/thread.
__global__ __launch_bounds__(256) void attn_kernel(
    const unsigned short* __restrict__ qh, const unsigned short* __restrict__ kh,
    const unsigned short* __restrict__ vt, const void* __restrict__ rpb,
    const unsigned short* __restrict__ pre,  // bf16 log2e-scaled bias or nullptr
    unsigned short* __restrict__ ctx, const int* __restrict__ flag) {
  __shared__ __align__(16) unsigned short Ks[2][4096];  // [buf][kk*2048 + s*32 + d']
  __shared__ __align__(16) unsigned short Vs[2][4096];  // [buf][kk*2048 + d*32 + s']
  __shared__ __align__(16) unsigned short Ps[4][1024];  // [wave][swizzled row*64+col]
  const int isf32 = flag[0];
  const int tid = threadIdx.x;
  const int wave = tid >> 6, lane = tid & 63, quad = lane >> 4, lrow = lane & 15;
  const int b = blockIdx.y & 7, h = blockIdx.y >> 3, bh = b * 16 + h;
  const int t0 = blockIdx.x * 64;

  const unsigned short* qbase = qh + ((long)(bh * 1024) + t0 + wave * 16 + lrow) * 64;
  bf16x8 qf0 = *(const bf16x8*)(qbase + quad * 8);
  bf16x8 qf1 = *(const bf16x8*)(qbase + 32 + quad * 8);

  const unsigned short* kbase = kh + (long)bh * 65536;
  const unsigned short* vbase = vt + (long)bh * 65536;

  // bias element (r,n) at s-tile s0: bidx0 + r*1024 + s0 + n*16
  const long bidx0 = ((long)h * 1024 + t0 + wave * 16 + quad * 4) * 1024 + lrow;
  const unsigned short* bs16 = pre ? pre : (const unsigned short*)rpb;
  const bool bf32 = (isf32 && pre == nullptr);
  const bool prescaled = (pre != nullptr);   // bias already *log2e?
  const float* bsf = (const float*)rpb;

  // staging: wave issues jobs j=2w,2w+1 for BOTH K and V.
  const int j0 = 2 * wave, j1 = j0 + 1;
  const int kk0 = j0 >> 2, ii0 = j0 & 3, kk1 = j1 >> 2, ii1 = j1 & 3;
  const int sr = lane >> 2, sc = (lane & 3) * 8;
  const unsigned short* kg0 = kbase + (long)(16 * ii0 + sr) * 64 + kk0 * 32 + sc;
  const unsigned short* kg1 = kbase + (long)(16 * ii1 + sr) * 64 + kk1 * 32 + sc;
  const unsigned short* vg0 = vbase + (long)(16 * ii0 + sr) * 1024 + kk0 * 32 + sc;
  const unsigned short* vg1 = vbase + (long)(16 * ii1 + sr) * 1024 + kk1 * 32 + sc;
  const int lo0 = kk0 * 2048 + ii0 * 512, lo1 = kk1 * 2048 + ii1 * 512;

  f32x4 oacc[4] = {};
  float rsum[4] = {0.f, 0.f, 0.f, 0.f};
  unsigned int bcur[4][4], bnxt[4][4];

  // prologue: stage tile 0 (K+V) and load bias(0); barrier drains vmcnt.
  gl_lds16(kg0, &Ks[0][lo0]);
  gl_lds16(kg1, &Ks[0][lo1]);
  gl_lds16(vg0, &Vs[0][lo0]);
  gl_lds16(vg1, &Vs[0][lo1]);
  if (bf32) {
#pragma unroll
    for (int r = 0; r < 4; ++r)
#pragma unroll
      for (int n = 0; n < 4; ++n)
        bcur[r][n] = __float_as_uint(bsf[bidx0 + r * 1024 + n * 16]);
  } else {
#pragma unroll
    for (int r = 0; r < 4; ++r)
#pragma unroll
      for (int n = 0; n < 4; ++n)
        bcur[r][n] = (unsigned int)bs16[bidx0 + r * 1024 + n * 16];
  }
  __syncthreads();

  for (int t = 0; t < 16; ++t) {
    const int cur = t & 1;
    const int s0 = t << 6;
    if (t < 15) {            // prefetch next tile: K,V -> LDS buf^1, bias -> regs
      const int sn = s0 + 64;
      gl_lds16(kg0 + (long)sn * 64, &Ks[cur ^ 1][lo0]);
      gl_lds16(kg1 + (long)sn * 64, &Ks[cur ^ 1][lo1]);
      gl_lds16(vg0 + sn, &Vs[cur ^ 1][lo0]);
      gl_lds16(vg1 + sn, &Vs[cur ^ 1][lo1]);
      if (bf32) {
#pragma unroll
        for (int r = 0; r < 4; ++r)
#pragma unroll
          for (int n = 0; n < 4; ++n)
            bnxt[r][n] = __float_as_uint(bsf[bidx0 + r * 1024 + sn + n * 16]);
      } else {
#pragma unroll
        for (int r = 0; r < 4; ++r)
#pragma unroll
          for (int n = 0; n < 4; ++n)
            bnxt[r][n] = (unsigned int)bs16[bidx0 + r * 1024 + sn + n * 16];
      }
    }

    f32x4 sacc[4] = {};
#pragma unroll
    for (int n = 0; n < 4; ++n) {
      bf16x8 kf0 = *(const bf16x8*)&Ks[cur][(n * 16 + lrow) * 32 + quad * 8];
      bf16x8 kf1 = *(const bf16x8*)&Ks[cur][2048 + (n * 16 + lrow) * 32 + quad * 8];
      sacc[n] = __builtin_amdgcn_mfma_f32_16x16x32_bf16(qf0, kf0, sacc[n], 0, 0, 0);
      sacc[n] = __builtin_amdgcn_mfma_f32_16x16x32_bf16(qf1, kf1, sacc[n], 0, 0, 0);
    }

    // softmax numerator: S' already log2e-scaled; bias scaled iff pre!=nullptr.
#pragma unroll
    for (int n = 0; n < 4; ++n)
#pragma unroll
      for (int rr = 0; rr < 2; ++rr) {
        const int r0 = 2 * rr, r1 = r0 + 1;
        float b0, b1;
        if (bf32) { b0 = __uint_as_float(bcur[r0][n]); b1 = __uint_as_float(bcur[r1][n]); }
        else      { b0 = bf2f((unsigned short)bcur[r0][n]); b1 = bf2f((unsigned short)bcur[r1][n]); }
        float x0, x1;
        if (prescaled) { x0 = sacc[n][r0] + b0; x1 = sacc[n][r1] + b1; }
        else { x0 = __builtin_fmaf(b0, LOG2E, sacc[n][r0]); x1 = __builtin_fmaf(b1, LOG2E, sacc[n][r1]); }
        const float p0 = fexp2(x0), p1 = fexp2(x1);
        rsum[r0] += p0; rsum[r1] += p1;
        unsigned int u;
        asm("v_cvt_pk_bf16_f32 %0, %1, %2" : "=v"(u) : "v"(p0), "v"(p1));
        const int row0 = quad * 4 + r0, row1 = row0 + 1;
        Ps[wave][(row0 * 64 + n * 16 + lrow) ^ ((row0 & 7) << 3)] = (unsigned short)u;
        Ps[wave][(row1 * 64 + n * 16 + lrow) ^ ((row1 & 7) << 3)] = (unsigned short)(u >> 16);
      }

    asm volatile("s_waitcnt lgkmcnt(0)" ::: "memory");  // Ps writes visible (same wave)

#pragma unroll
    for (int kk = 0; kk < 2; ++kk) {
      bf16x8 pf = *(const bf16x8*)&Ps[wave][(lrow * 64 + kk * 32 + quad * 8) ^ ((lrow & 7) << 3)];
#pragma unroll
      for (int n = 0; n < 4; ++n) {
        bf16x8 vf = *(const bf16x8*)&Vs[cur][kk * 2048 + (n * 16 + lrow) * 32 + quad * 8];
        oacc[n] = __builtin_amdgcn_mfma_f32_16x16x32_bf16(pf, vf, oacc[n], 0, 0, 0);
      }
    }
    __syncthreads();   // vmcnt(0): next-tile stage landed; WAR fence for buf flip
    if (t < 15) {
#pragma unroll
      for (int r = 0; r < 4; ++r)
#pragma unroll
        for (int n = 0; n < 4; ++n) bcur[r][n] = bnxt[r][n];
    }
  }

  // single deferred reduction: sum over the 16 lanes (lrow) sharing this quad
#pragma unroll
  for (int msk = 1; msk <= 8; msk <<= 1)
#pragma unroll
    for (int r = 0; r < 4; ++r)
      rsum[r] += __shfl_xor(rsum[r], msk, 64);

  float linv[4];
#pragma unroll
  for (int r = 0; r < 4; ++r) linv[r] = 1.0f / rsum[r];
#pragma unroll
  for (int n = 0; n < 4; ++n)
#pragma unroll
    for (int r = 0; r < 4; ++r) {
      const int t = t0 + wave * 16 + quad * 4 + r;
      ctx[((long)t * 8 + b) * 1024 + h * 64 + n * 16 + lrow] = f2bf(oacc[n][r] * linv[r]);
    }
}

// ---------------------------------------------------------------------------
// Kernel 4: out-proj GEMM, 128x128 tile, BK=64, 1-phase staging (R5).
__global__ __launch_bounds__(256) void outproj_kernel(
    const unsigned short* __restrict__ ctx, const unsigned short* __restrict__ weff,
    const void* __restrict__ bias, void* __restrict__ out,
    const int* __restrict__ flag) {
  __shared__ __align__(16) unsigned short As[2 * 128 * 32];
  __shared__ __align__(16) unsigned short Bs[2 * 128 * 32];
  const int isf32 = flag[0];
  const int tid = threadIdx.x;
  const int wave = tid >> 6, lane = tid & 63, quad = lane >> 4, lrow = lane & 15;
  const int wr0 = (wave >> 1) * 64, wc0 = (wave & 1) * 64;
  const int fbase = blockIdx.x * 128, mbase = blockIdx.y * 128;
  const int srow = lane >> 2, scol = (lane & 3) * 8;
  const unsigned short* ag  = ctx  + (long)(mbase + 32 * wave + srow) * 1024 + scol;
  const unsigned short* ag2 = ag + 16 * 1024;
  const unsigned short* bg  = weff + (long)(fbase + 32 * wave + srow) * 1024 + scol;
  const unsigned short* bg2 = bg + 16 * 1024;
  unsigned short* la  = &As[(32 * wave) * 32];
  unsigned short* la2 = &As[(32 * wave + 16) * 32];
  unsigned short* lb  = &Bs[(32 * wave) * 32];
  unsigned short* lb2 = &Bs[(32 * wave + 16) * 32];

  f32x4 acc[4][4] = {};
  for (int k0 = 0; k0 < 1024; k0 += 64) {
    gl_lds16(ag + k0, la);
    gl_lds16(ag2 + k0, la2);
    gl_lds16(ag + k0 + 32, la + 4096);
    gl_lds16(ag2 + k0 + 32, la2 + 4096);
    gl_lds16(bg + k0, lb);
    gl_lds16(bg2 + k0, lb2);
    gl_lds16(bg + k0 + 32, lb + 4096);
    gl_lds16(bg2 + k0 + 32, lb2 + 4096);
    __syncthreads();
#pragma unroll
    for (int kk = 0; kk < 2; ++kk) {
      bf16x8 af[4], bfv[4];
#pragma unroll
      for (int mi = 0; mi < 4; ++mi)
        af[mi] = *(const bf16x8*)&As[kk * 4096 + (wr0 + mi * 16 + lrow) * 32 + quad * 8];
#pragma unroll
      for (int ni = 0; ni < 4; ++ni)
        bfv[ni] = *(const bf16x8*)&Bs[kk * 4096 + (wc0 + ni * 16 + lrow) * 32 + quad * 8];
#pragma unroll
      for (int mi = 0; mi < 4; ++mi)
#pragma unroll
        for (int ni = 0; ni < 4; ++ni)
          acc[mi][ni] = __builtin_amdgcn_mfma_f32_16x16x32_bf16(af[mi], bfv[ni], acc[mi][ni], 0, 0, 0);
    }
    __syncthreads();
  }
#pragma unroll
  for (int ni = 0; ni < 4; ++ni) {
    const int f = fbase + wc0 + ni * 16 + lrow;
    const float bv = ld_in(bias, f, isf32);
#pragma unroll
    for (int mi = 0; mi < 4; ++mi)
#pragma unroll
      for (int r = 0; r < 4; ++r) {
        const int m = mbase + wr0 + mi * 16 + quad * 4 + r;
        const float val = acc[mi][ni][r] + bv;
        if (isf32) ((float*)out)[(long)m * 1024 + f] = val;
        else       ((unsigned short*)out)[(long)m * 1024 + f] = f2bf(val);
      }
  }
}

// ---------------------------------------------------------------------------
extern "C" void kernel_launch(void* const* d_in, const int* in_sizes, int n_in,
                              void* d_out, int out_size, void* d_ws, size_t ws_size,
                              hipStream_t stream) {
  (void)out_size;
  static const int EXP[10] = {8388608, 3145728, 3072, 49152, 16384,
                              1048576, 1024, 16384, 16384, 16777216};
  if (n_in != 10) return;
  for (int i = 0; i < 10; ++i) if (in_sizes[i] != EXP[i]) return;

  const void* query = d_in[0];
  const void* ipw = d_in[1];  const void* ipb = d_in[2];
  const void* il  = d_in[3];  const void* ir  = d_in[4];
  const void* opw = d_in[5];  const void* opb = d_in[6];
  const void* ol  = d_in[7];  const void* orr = d_in[8];
  const void* rpb = d_in[9];

  // ws: flag | W_in_eff 3072x1024 | W_out_eff 1024x1024 | q | k | vT | ctx
  //     (each 8192x1024) | rpb_bf16 16M.  qbf aliases ctx (dead until attn).
  int* flag = (int*)d_ws;
  unsigned short* base = (unsigned short*)d_ws + 16;
  unsigned short* w_in_eff  = base;
  unsigned short* w_out_eff = w_in_eff + (long)3072 * 1024;
  unsigned short* qh  = w_out_eff + (long)1024 * 1024;
  unsigned short* kh  = qh + 8388608L;
  unsigned short* vt  = kh + 8388608L;
  unsigned short* ctx = vt + 8388608L;
  unsigned short* rpbbf = ctx + 8388608L;
  unsigned short* qbf = ctx;  // alias: qbf consumed by inproj before attn writes ctx
  const size_t NEED_FULL = 32 + (3145728L + 1048576L + 4L * 8388608L + 16777216L) * 2;
  const bool big = ws_size >= NEED_FULL;

  detect_kernel<<<dim3(1), dim3(64), 0, stream>>>((const unsigned int*)query, flag);
  if (big)
    convert_bias<<<dim3(8192), dim3(256), 0, stream>>>(rpb, rpbbf, flag);
  convert_q<<<dim3(4096), dim3(256), 0, stream>>>(query, qbf, flag);
  eff_weights<<<dim3(12288), dim3(256), 0, stream>>>(ipw, il, ir, w_in_eff, flag);
  eff_weights<<<dim3(4096), dim3(256), 0, stream>>>(opw, ol, orr, w_out_eff, flag);
  inproj_kernel<<<dim3(24, 64), dim3(256), 0, stream>>>(qbf, w_in_eff, ipb, qh, kh, vt, flag);
  attn_kernel<<<dim3(16, 128), dim3(256), 0, stream>>>(qh, kh, vt, rpb,
                                                       big ? rpbbf : nullptr, ctx, flag);
  outproj_kernel<<<dim3(8, 64), dim3(256), 0, stream>>>(ctx, w_out_eff, opb, d_out, flag);
}

// Round 8
// 396.480 us; speedup vs baseline: 1.1116x; 1.0106x over previous
//
#include <hip/hip_runtime.h>
#include <hip/hip_bf16.h>

// Problem dims (fixed): T=1024 B=8 E=1024 H=16 hd=64 R=16, M=T*B=8192, F=3*E=3072
// Inputs f32 (runtime-detected; bf16 fallback). Intermediates bf16, fp32 accum.
// exp2 trick: Q pre-scaled by 0.125*log2e, bias bf16 copy pre-scaled by log2e,
// so softmax uses raw v_exp_f32 (2^x) with no per-element multiply.

typedef __attribute__((ext_vector_type(8))) __bf16 bf16x8;
typedef __attribute__((ext_vector_type(4))) float f32x4;

#define LOG2E 1.44269504f

__device__ __forceinline__ float bf2f(unsigned short u) {
  union { unsigned int i; float f; } v; v.i = ((unsigned int)u) << 16; return v.f;
}
__device__ __forceinline__ unsigned short f2bf(float f) {
  union { float f; unsigned int i; } v; v.f = f;
  unsigned int x = v.i;
  unsigned int r = x + 0x7FFFu + ((x >> 16) & 1u);
  return (unsigned short)(r >> 16);
}
__device__ __forceinline__ unsigned int pack2(float a, float b) {
  return (unsigned int)f2bf(a) | ((unsigned int)f2bf(b) << 16);
}
__device__ __forceinline__ float ld_in(const void* p, long idx, int isf32) {
  if (isf32) return ((const float*)p)[idx];
  return bf2f(((const unsigned short*)p)[idx]);
}
__device__ __forceinline__ float fexp2(float x) {
#if __has_builtin(__builtin_amdgcn_exp2f)
  return __builtin_amdgcn_exp2f(x);
#else
  return __expf(x * 0.69314718056f);
#endif
}
// async global->LDS, 16 B per lane; LDS dst = wave-uniform base + lane*16
__device__ __forceinline__ void gl_lds16(const unsigned short* g, unsigned short* l) {
  __builtin_amdgcn_global_load_lds(
      (const __attribute__((address_space(1))) unsigned int*)g,
      (__attribute__((address_space(3))) unsigned int*)l, 16, 0, 0);
}

// ---------------------------------------------------------------------------
// Kernel 0: dtype detector (f32-stored vs bf16-packed).
__global__ void detect_kernel(const unsigned int* __restrict__ q, int* __restrict__ flag) {
  __shared__ int cnt;
  if (threadIdx.x == 0) cnt = 0;
  __syncthreads();
  unsigned int w = q[threadIdx.x];
  int c = 0;
  if (((w >> 7) & 0xFFu) >= 0xC0u) c++;
  if (((w >> 23) & 0xFFu) >= 0xC0u) c++;
  atomicAdd(&cnt, c);
  __syncthreads();
  if (threadIdx.x == 0) flag[0] = (cnt >= 2) ? 1 : 0;
}

// ---------------------------------------------------------------------------
// Kernel 0b: bias -> bf16 PRE-SCALED by log2e (8 elems/thread).
__global__ __launch_bounds__(256) void convert_bias(
    const void* __restrict__ in, unsigned short* __restrict__ out,
    const int* __restrict__ flag) {
  long idx = ((long)blockIdx.x * 256 + threadIdx.x) * 8;
  if (flag[0]) {
    const float* p = (const float*)in + idx;
    float4 a = ((const float4*)p)[0], b = ((const float4*)p)[1];
    uint4 v;
    v.x = pack2(a.x * LOG2E, a.y * LOG2E); v.y = pack2(a.z * LOG2E, a.w * LOG2E);
    v.z = pack2(b.x * LOG2E, b.y * LOG2E); v.w = pack2(b.z * LOG2E, b.w * LOG2E);
    *(uint4*)(out + idx) = v;
  } else {
    const unsigned short* p = (const unsigned short*)in + idx;
    unsigned short s[8];
#pragma unroll
    for (int i = 0; i < 8; ++i) s[i] = f2bf(bf2f(p[i]) * LOG2E);
    uint4 v;
    v.x = (unsigned int)s[0] | ((unsigned int)s[1] << 16);
    v.y = (unsigned int)s[2] | ((unsigned int)s[3] << 16);
    v.z = (unsigned int)s[4] | ((unsigned int)s[5] << 16);
    v.w = (unsigned int)s[6] | ((unsigned int)s[7] << 16);
    *(uint4*)(out + idx) = v;
  }
}

// ---------------------------------------------------------------------------
// Kernel 0c: query convert with row permutation (T,B,E) -> (B,T,E).
__global__ __launch_bounds__(256) void convert_q(
    const void* __restrict__ in, unsigned short* __restrict__ out,
    const int* __restrict__ flag) {
  long idx = ((long)blockIdx.x * 256 + threadIdx.x) * 8;
  const int inrow = (int)(idx >> 10);
  const int e = (int)(idx & 1023);
  const long oidx = ((long)((inrow & 7) << 10 | (inrow >> 3))) * 1024 + e;
  if (flag[0]) {
    const float* p = (const float*)in + idx;
    float4 a = ((const float4*)p)[0], b = ((const float4*)p)[1];
    uint4 v;
    v.x = pack2(a.x, a.y); v.y = pack2(a.z, a.w);
    v.z = pack2(b.x, b.y); v.w = pack2(b.z, b.w);
    *(uint4*)(out + oidx) = v;
  } else {
    *(uint4*)(out + oidx) = *(const uint4*)((const unsigned short*)in + idx);
  }
}

// ---------------------------------------------------------------------------
// Kernel 1: W_eff = W + left @ right (rank-16), bf16 out.
__global__ __launch_bounds__(256) void eff_weights(
    const void* __restrict__ w, const void* __restrict__ left,
    const void* __restrict__ right, unsigned short* __restrict__ outw,
    const int* __restrict__ flag) {
  const int isf32 = flag[0];
  long idx = (long)blockIdx.x * 256 + threadIdx.x;
  long f = idx >> 10, e = idx & 1023;
  float acc = ld_in(w, idx, isf32);
#pragma unroll
  for (int r = 0; r < 16; ++r)
    acc += ld_in(left, (f << 4) + r, isf32) * ld_in(right, (r << 10) + e, isf32);
  outw[idx] = f2bf(acc);
}

// ---------------------------------------------------------------------------
// Kernel 2: in-proj GEMM, 128x128 tile, BK=64, 1-phase global_load_lds
// staging (R5-verified; R4 lesson: no 2-phase dbuf graft here).
// q epilogue scale = 0.125*log2e (exp2 trick).
__global__ __launch_bounds__(256) void inproj_kernel(
    const unsigned short* __restrict__ qbf,    // (8,1024,1024) bf16, row=b*1024+t
    const unsigned short* __restrict__ weff,   // (3072,1024) bf16
    const void* __restrict__ bias,             // (3072)
    unsigned short* __restrict__ qh, unsigned short* __restrict__ kh,
    unsigned short* __restrict__ vt, const int* __restrict__ flag) {
  __shared__ __align__(16) unsigned short As[2 * 128 * 32];  // [kk][row][32]
  __shared__ __align__(16) unsigned short Bs[2 * 128 * 32];
  const int isf32 = flag[0];
  const int tid = threadIdx.x;
  const int wave = tid >> 6, lane = tid & 63, quad = lane >> 4, lrow = lane & 15;
  const int wr0 = (wave >> 1) * 64, wc0 = (wave & 1) * 64;
  const int fbase = blockIdx.x * 128, mbase = blockIdx.y * 128;
  const int srow = lane >> 2, scol = (lane & 3) * 8;
  const unsigned short* ag  = qbf  + (long)(mbase + 32 * wave + srow) * 1024 + scol;
  const unsigned short* ag2 = ag + 16 * 1024;
  const unsigned short* bg  = weff + (long)(fbase + 32 * wave + srow) * 1024 + scol;
  const unsigned short* bg2 = bg + 16 * 1024;
  unsigned short* la  = &As[(32 * wave) * 32];
  unsigned short* la2 = &As[(32 * wave + 16) * 32];
  unsigned short* lb  = &Bs[(32 * wave) * 32];
  unsigned short* lb2 = &Bs[(32 * wave + 16) * 32];

  f32x4 acc[4][4] = {};
  for (int k0 = 0; k0 < 1024; k0 += 64) {
    gl_lds16(ag + k0, la);
    gl_lds16(ag2 + k0, la2);
    gl_lds16(ag + k0 + 32, la + 4096);
    gl_lds16(ag2 + k0 + 32, la2 + 4096);
    gl_lds16(bg + k0, lb);
    gl_lds16(bg2 + k0, lb2);
    gl_lds16(bg + k0 + 32, lb + 4096);
    gl_lds16(bg2 + k0 + 32, lb2 + 4096);
    __syncthreads();             // drains vmcnt: staged data visible
#pragma unroll
    for (int kk = 0; kk < 2; ++kk) {
      bf16x8 af[4], bfv[4];
#pragma unroll
      for (int mi = 0; mi < 4; ++mi)
        af[mi] = *(const bf16x8*)&As[kk * 4096 + (wr0 + mi * 16 + lrow) * 32 + quad * 8];
#pragma unroll
      for (int ni = 0; ni < 4; ++ni)
        bfv[ni] = *(const bf16x8*)&Bs[kk * 4096 + (wc0 + ni * 16 + lrow) * 32 + quad * 8];
#pragma unroll
      for (int mi = 0; mi < 4; ++mi)
#pragma unroll
        for (int ni = 0; ni < 4; ++ni)
          acc[mi][ni] = __builtin_amdgcn_mfma_f32_16x16x32_bf16(af[mi], bfv[ni], acc[mi][ni], 0, 0, 0);
    }
    __syncthreads();             // protect LDS before next stage
  }
  const int which = fbase >> 10;               // 0=q 1=k 2=v (uniform per block)
  const int h = ((fbase + wc0) >> 6) & 15;     // wave's 64 cols = one head
  const int bq = mbase >> 10;                  // uniform batch index per block
  const int tbase = (mbase & 1023) + wr0;
#pragma unroll
  for (int ni = 0; ni < 4; ++ni) {
    const int d = ni * 16 + lrow;
    const float bv = ld_in(bias, fbase + wc0 + d, isf32);
    if (which == 2) {
      unsigned short* vrow = vt + ((long)(bq * 16 + h) * 64 + d) * 1024;
#pragma unroll
      for (int mi = 0; mi < 4; ++mi) {
        const int t = tbase + mi * 16 + quad * 4;
        ushort4 v;
        v.x = f2bf(acc[mi][ni][0] + bv);
        v.y = f2bf(acc[mi][ni][1] + bv);
        v.z = f2bf(acc[mi][ni][2] + bv);
        v.w = f2bf(acc[mi][ni][3] + bv);
        *(ushort4*)(vrow + t) = v;
      }
    } else {
      unsigned short* qk = (which == 0) ? qh : kh;
      const float sc = (which == 0) ? (0.125f * LOG2E) : 1.0f;
      unsigned short* row0 = qk + (long)(bq * 16 + h) * 65536;
#pragma unroll
      for (int mi = 0; mi < 4; ++mi)
#pragma unroll
        for (int r = 0; r < 4; ++r) {
          const int t = tbase + mi * 16 + quad * 4 + r;
          row0[(long)t * 64 + d] = f2bf((acc[mi][ni][r] + bv) * sc);
        }
    }
  }
}

// ---------------------------------------------------------------------------
// Kernel 3: attention. v7: 8-wave (512-thread) blocks covering 128 q-rows.
// R7 post-mortem: 4-wave version was TLP-starved (MfmaUtil 14, VALU 47,
// HBM 23, occ 28 — nothing saturated; serial per-wave chain dominated).
// 8 waves share each staged K/V s-tile (K/V are per-(b,h), q-row-invariant):
// staging per unit work halves (1 K + 1 V gl_lds16 per wave per iter), and
// LDS 48 KB -> 3 blocks x 8 waves = 24 waves/CU (was ~9). Sync structure
// UNCHANGED from the R3-verified 2-phase: one barrier/iter; WAR on buf^1
// fenced by prev barrier, RAW on buf by the barrier's vmcnt drain.
__global__ __launch_bounds__(512) void attn_kernel(
    const unsigned short* __restrict__ qh, const unsigned short* __restrict__ kh,
    const unsigned short* __restrict__ vt, const void* __restrict__ rpb,
    const unsigned short* __restrict__ pre,  // bf16 log2e-scaled bias or nullptr
    unsigned short* __restrict__ ctx, const int* __restrict__ flag) {
  __shared__ __align__(16) unsigned short Ks[2][4096];  // [buf][kk*2048 + s*32 + d']
  __shared__ __align__(16) unsigned short Vs[2][4096];  // [buf][kk*2048 + d*32 + s']
  __shared__ __align__(16) unsigned short Ps[8][1024];  // [wave][swizzled row*64+col]
  const int isf32 = flag[0];
  const int tid = threadIdx.x;
  const int wave = tid >> 6, lane = tid & 63, quad = lane >> 4, lrow = lane & 15;
  const int b = blockIdx.y & 7, h = blockIdx.y >> 3, bh = b * 16 + h;
  const int t0 = blockIdx.x * 128;

  const unsigned short* qbase = qh + ((long)(bh * 1024) + t0 + wave * 16 + lrow) * 64;
  bf16x8 qf0 = *(const bf16x8*)(qbase + quad * 8);
  bf16x8 qf1 = *(const bf16x8*)(qbase + 32 + quad * 8);

  const unsigned short* kbase = kh + (long)bh * 65536;
  const unsigned short* vbase = vt + (long)bh * 65536;

  // bias element (r,n) at s-tile s0: bidx0 + r*1024 + s0 + n*16
  const long bidx0 = ((long)h * 1024 + t0 + wave * 16 + quad * 4) * 1024 + lrow;
  const unsigned short* bs16 = pre ? pre : (const unsigned short*)rpb;
  const bool bf32 = (isf32 && pre == nullptr);
  const bool prescaled = (pre != nullptr);   // bias already *log2e?
  const float* bsf = (const float*)rpb;

  // staging: wave w issues job w for K and job w for V.
  // job -> kk=w>>2 (32-col half), ii=w&3 (16-row chunk).
  const int kkj = wave >> 2, iij = wave & 3;
  const int sr = lane >> 2, sc = (lane & 3) * 8;
  const unsigned short* kg = kbase + (long)(16 * iij + sr) * 64 + kkj * 32 + sc;
  const unsigned short* vg = vbase + (long)(16 * iij + sr) * 1024 + kkj * 32 + sc;
  const int lo = kkj * 2048 + iij * 512;

  f32x4 oacc[4] = {};
  float rsum[4] = {0.f, 0.f, 0.f, 0.f};
  unsigned int bcur[4][4], bnxt[4][4];

  // prologue: stage tile 0 (K+V) and load bias(0); barrier drains vmcnt.
  gl_lds16(kg, &Ks[0][lo]);
  gl_lds16(vg, &Vs[0][lo]);
  if (bf32) {
#pragma unroll
    for (int r = 0; r < 4; ++r)
#pragma unroll
      for (int n = 0; n < 4; ++n)
        bcur[r][n] = __float_as_uint(bsf[bidx0 + r * 1024 + n * 16]);
  } else {
#pragma unroll
    for (int r = 0; r < 4; ++r)
#pragma unroll
      for (int n = 0; n < 4; ++n)
        bcur[r][n] = (unsigned int)bs16[bidx0 + r * 1024 + n * 16];
  }
  __syncthreads();

  for (int t = 0; t < 16; ++t) {
    const int cur = t & 1;
    const int s0 = t << 6;
    if (t < 15) {            // prefetch next tile: K,V -> LDS buf^1, bias -> regs
      const int sn = s0 + 64;
      gl_lds16(kg + (long)sn * 64, &Ks[cur ^ 1][lo]);
      gl_lds16(vg + sn, &Vs[cur ^ 1][lo]);
      if (bf32) {
#pragma unroll
        for (int r = 0; r < 4; ++r)
#pragma unroll
          for (int n = 0; n < 4; ++n)
            bnxt[r][n] = __float_as_uint(bsf[bidx0 + r * 1024 + sn + n * 16]);
      } else {
#pragma unroll
        for (int r = 0; r < 4; ++r)
#pragma unroll
          for (int n = 0; n < 4; ++n)
            bnxt[r][n] = (unsigned int)bs16[bidx0 + r * 1024 + sn + n * 16];
      }
    }

    f32x4 sacc[4] = {};
#pragma unroll
    for (int n = 0; n < 4; ++n) {
      bf16x8 kf0 = *(const bf16x8*)&Ks[cur][(n * 16 + lrow) * 32 + quad * 8];
      bf16x8 kf1 = *(const bf16x8*)&Ks[cur][2048 + (n * 16 + lrow) * 32 + quad * 8];
      sacc[n] = __builtin_amdgcn_mfma_f32_16x16x32_bf16(qf0, kf0, sacc[n], 0, 0, 0);
      sacc[n] = __builtin_amdgcn_mfma_f32_16x16x32_bf16(qf1, kf1, sacc[n], 0, 0, 0);
    }

    // softmax numerator: S' already log2e-scaled; bias scaled iff pre!=nullptr.
#pragma unroll
    for (int n = 0; n < 4; ++n)
#pragma unroll
      for (int rr = 0; rr < 2; ++rr) {
        const int r0 = 2 * rr, r1 = r0 + 1;
        float b0, b1;
        if (bf32) { b0 = __uint_as_float(bcur[r0][n]); b1 = __uint_as_float(bcur[r1][n]); }
        else      { b0 = bf2f((unsigned short)bcur[r0][n]); b1 = bf2f((unsigned short)bcur[r1][n]); }
        float x0, x1;
        if (prescaled) { x0 = sacc[n][r0] + b0; x1 = sacc[n][r1] + b1; }
        else { x0 = __builtin_fmaf(b0, LOG2E, sacc[n][r0]); x1 = __builtin_fmaf(b1, LOG2E, sacc[n][r1]); }
        const float p0 = fexp2(x0), p1 = fexp2(x1);
        rsum[r0] += p0; rsum[r1] += p1;
        unsigned int u;
        asm("v_cvt_pk_bf16_f32 %0, %1, %2" : "=v"(u) : "v"(p0), "v"(p1));
        const int row0 = quad * 4 + r0, row1 = row0 + 1;
        Ps[wave][(row0 * 64 + n * 16 + lrow) ^ ((row0 & 7) << 3)] = (unsigned short)u;
        Ps[wave][(row1 * 64 + n * 16 + lrow) ^ ((row1 & 7) << 3)] = (unsigned short)(u >> 16);
      }

    asm volatile("s_waitcnt lgkmcnt(0)" ::: "memory");  // Ps writes visible (same wave)

#pragma unroll
    for (int kk = 0; kk < 2; ++kk) {
      bf16x8 pf = *(const bf16x8*)&Ps[wave][(lrow * 64 + kk * 32 + quad * 8) ^ ((lrow & 7) << 3)];
#pragma unroll
      for (int n = 0; n < 4; ++n) {
        bf16x8 vf = *(const bf16x8*)&Vs[cur][kk * 2048 + (n * 16 + lrow) * 32 + quad * 8];
        oacc[n] = __builtin_amdgcn_mfma_f32_16x16x32_bf16(pf, vf, oacc[n], 0, 0, 0);
      }
    }
    __syncthreads();   // vmcnt(0): next-tile stage landed; WAR fence for buf flip
    if (t < 15) {
#pragma unroll
      for (int r = 0; r < 4; ++r)
#pragma unroll
        for (int n = 0; n < 4; ++n) bcur[r][n] = bnxt[r][n];
    }
  }

  // single deferred reduction: sum over the 16 lanes (lrow) sharing this quad
#pragma unroll
  for (int msk = 1; msk <= 8; msk <<= 1)
#pragma unroll
    for (int r = 0; r < 4; ++r)
      rsum[r] += __shfl_xor(rsum[r], msk, 64);

  float linv[4];
#pragma unroll
  for (int r = 0; r < 4; ++r) linv[r] = 1.0f / rsum[r];
#pragma unroll
  for (int n = 0; n < 4; ++n)
#pragma unroll
    for (int r = 0; r < 4; ++r) {
      const int t = t0 + wave * 16 + quad * 4 + r;
      ctx[((long)t * 8 + b) * 1024 + h * 64 + n * 16 + lrow] = f2bf(oacc[n][r] * linv[r]);
    }
}

// ---------------------------------------------------------------------------
// Kernel 4: out-proj GEMM, 128x128 tile, BK=64, 1-phase staging (R5).
__global__ __launch_bounds__(256) void outproj_kernel(
    const unsigned short* __restrict__ ctx, const unsigned short* __restrict__ weff,
    const void* __restrict__ bias, void* __restrict__ out,
    const int* __restrict__ flag) {
  __shared__ __align__(16) unsigned short As[2 * 128 * 32];
  __shared__ __align__(16) unsigned short Bs[2 * 128 * 32];
  const int isf32 = flag[0];
  const int tid = threadIdx.x;
  const int wave = tid >> 6, lane = tid & 63, quad = lane >> 4, lrow = lane & 15;
  const int wr0 = (wave >> 1) * 64, wc0 = (wave & 1) * 64;
  const int fbase = blockIdx.x * 128, mbase = blockIdx.y * 128;
  const int srow = lane >> 2, scol = (lane & 3) * 8;
  const unsigned short* ag  = ctx  + (long)(mbase + 32 * wave + srow) * 1024 + scol;
  const unsigned short* ag2 = ag + 16 * 1024;
  const unsigned short* bg  = weff + (long)(fbase + 32 * wave + srow) * 1024 + scol;
  const unsigned short* bg2 = bg + 16 * 1024;
  unsigned short* la  = &As[(32 * wave) * 32];
  unsigned short* la2 = &As[(32 * wave + 16) * 32];
  unsigned short* lb  = &Bs[(32 * wave) * 32];
  unsigned short* lb2 = &Bs[(32 * wave + 16) * 32];

  f32x4 acc[4][4] = {};
  for (int k0 = 0; k0 < 1024; k0 += 64) {
    gl_lds16(ag + k0, la);
    gl_lds16(ag2 + k0, la2);
    gl_lds16(ag + k0 + 32, la + 4096);
    gl_lds16(ag2 + k0 + 32, la2 + 4096);
    gl_lds16(bg + k0, lb);
    gl_lds16(bg2 + k0, lb2);
    gl_lds16(bg + k0 + 32, lb + 4096);
    gl_lds16(bg2 + k0 + 32, lb2 + 4096);
    __syncthreads();
#pragma unroll
    for (int kk = 0; kk < 2; ++kk) {
      bf16x8 af[4], bfv[4];
#pragma unroll
      for (int mi = 0; mi < 4; ++mi)
        af[mi] = *(const bf16x8*)&As[kk * 4096 + (wr0 + mi * 16 + lrow) * 32 + quad * 8];
#pragma unroll
      for (int ni = 0; ni < 4; ++ni)
        bfv[ni] = *(const bf16x8*)&Bs[kk * 4096 + (wc0 + ni * 16 + lrow) * 32 + quad * 8];
#pragma unroll
      for (int mi = 0; mi < 4; ++mi)
#pragma unroll
        for (int ni = 0; ni < 4; ++ni)
          acc[mi][ni] = __builtin_amdgcn_mfma_f32_16x16x32_bf16(af[mi], bfv[ni], acc[mi][ni], 0, 0, 0);
    }
    __syncthreads();
  }
#pragma unroll
  for (int ni = 0; ni < 4; ++ni) {
    const int f = fbase + wc0 + ni * 16 + lrow;
    const float bv = ld_in(bias, f, isf32);
#pragma unroll
    for (int mi = 0; mi < 4; ++mi)
#pragma unroll
      for (int r = 0; r < 4; ++r) {
        const int m = mbase + wr0 + mi * 16 + quad * 4 + r;
        const float val = acc[mi][ni][r] + bv;
        if (isf32) ((float*)out)[(long)m * 1024 + f] = val;
        else       ((unsigned short*)out)[(long)m * 1024 + f] = f2bf(val);
      }
  }
}

// ---------------------------------------------------------------------------
extern "C" void kernel_launch(void* const* d_in, const int* in_sizes, int n_in,
                              void* d_out, int out_size, void* d_ws, size_t ws_size,
                              hipStream_t stream) {
  (void)out_size;
  static const int EXP[10] = {8388608, 3145728, 3072, 49152, 16384,
                              1048576, 1024, 16384, 16384, 16777216};
  if (n_in != 10) return;
  for (int i = 0; i < 10; ++i) if (in_sizes[i] != EXP[i]) return;

  const void* query = d_in[0];
  const void* ipw = d_in[1];  const void* ipb = d_in[2];
  const void* il  = d_in[3];  const void* ir  = d_in[4];
  const void* opw = d_in[5];  const void* opb = d_in[6];
  const void* ol  = d_in[7];  const void* orr = d_in[8];
  const void* rpb = d_in[9];

  // ws: flag | W_in_eff 3072x1024 | W_out_eff 1024x1024 | q | k | vT | ctx
  //     (each 8192x1024) | rpb_bf16 16M.  qbf aliases ctx (dead until attn).
  int* flag = (int*)d_ws;
  unsigned short* base = (unsigned short*)d_ws + 16;
  unsigned short* w_in_eff  = base;
  unsigned short* w_out_eff = w_in_eff + (long)3072 * 1024;
  unsigned short* qh  = w_out_eff + (long)1024 * 1024;
  unsigned short* kh  = qh + 8388608L;
  unsigned short* vt  = kh + 8388608L;
  unsigned short* ctx = vt + 8388608L;
  unsigned short* rpbbf = ctx + 8388608L;
  unsigned short* qbf = ctx;  // alias: qbf consumed by inproj before attn writes ctx
  const size_t NEED_FULL = 32 + (3145728L + 1048576L + 4L * 8388608L + 16777216L) * 2;
  const bool big = ws_size >= NEED_FULL;

  detect_kernel<<<dim3(1), dim3(64), 0, stream>>>((const unsigned int*)query, flag);
  if (big)
    convert_bias<<<dim3(8192), dim3(256), 0, stream>>>(rpb, rpbbf, flag);
  convert_q<<<dim3(4096), dim3(256), 0, stream>>>(query, qbf, flag);
  eff_weights<<<dim3(12288), dim3(256), 0, stream>>>(ipw, il, ir, w_in_eff, flag);
  eff_weights<<<dim3(4096), dim3(256), 0, stream>>>(opw, ol, orr, w_out_eff, flag);
  inproj_kernel<<<dim3(24, 64), dim3(256), 0, stream>>>(qbf, w_in_eff, ipb, qh, kh, vt, flag);
  attn_kernel<<<dim3(8, 128), dim3(512), 0, stream>>>(qh, kh, vt, rpb,
                                                      big ? rpbbf : nullptr, ctx, flag);
  outproj_kernel<<<dim3(8, 64), dim3(256), 0, stream>>>(ctx, w_out_eff, opb, d_out, flag);
}